// Round 1
// baseline (326.819 us; speedup 1.0000x reference)
//
#include <hip/hip_runtime.h>
#include <hip/hip_bf16.h>

#define B_ 2
#define S_ 2048
#define D_ 1024
#define N_ 16
#define R_ 64
#define NC 64          // number of scan chunks
#define CL 32          // chunk length  (NC*CL == S_)
#define BS_ (B_*S_)

// ---------------- projections: dt -> delta, B, C ----------------
// one block handles 8 tokens; weights served from L2, x staged in LDS
__global__ __launch_bounds__(256) void k_proj(
    const float* __restrict__ x, const float* __restrict__ W_dtw,
    const float* __restrict__ W_dt, const float* __restrict__ b_dt,
    const float* __restrict__ W_B, const float* __restrict__ W_C,
    float* __restrict__ delta, float* __restrict__ Bm, float* __restrict__ Cm) {
  __shared__ __align__(16) float xs[8][1028];   // pad 4: bank-spread + 16B align
  __shared__ float dts[8][68];
  const int t0 = blockIdx.x * 8;
  const int tid = threadIdx.x;

  // load 8 token rows (32KB), coalesced float4
  for (int p = tid; p < 8 * 256; p += 256) {
    int tok = p >> 8;
    int i4 = (p & 255) * 4;
    float4 v = *(const float4*)&x[((size_t)(t0 + tok)) * D_ + i4];
    *(float4*)&xs[tok][i4] = v;
  }
  __syncthreads();

  // phase A: 96 dot-products (64 dt, 16 B, 16 C) x 8 tokens
  for (int p = tid; p < 96 * 8; p += 256) {
    int tok = p & 7;
    int o = p >> 3;
    const float* wrow = (o < 64) ? (W_dtw + (size_t)o * D_)
                      : (o < 80) ? (W_B + (size_t)(o - 64) * D_)
                                 : (W_C + (size_t)(o - 80) * D_);
    float acc = 0.f;
    #pragma unroll 8
    for (int k = 0; k < D_; ++k) acc += xs[tok][k] * wrow[k];
    if (o < 64)      dts[tok][o] = acc;
    else if (o < 80) Bm[(size_t)(t0 + tok) * N_ + (o - 64)] = acc;
    else             Cm[(size_t)(t0 + tok) * N_ + (o - 80)] = acc;
  }
  __syncthreads();

  // phase B: delta[d] = softplus(dt . W_dt[d] + b_dt[d])
  for (int p = tid; p < 8 * D_; p += 256) {
    int tok = p & 7;
    int d = p >> 3;
    const float* wrow = W_dt + (size_t)d * R_;
    float acc = b_dt[d];
    #pragma unroll 8
    for (int r = 0; r < R_; ++r) acc += dts[tok][r] * wrow[r];
    float sp = fmaxf(acc, 0.f) + log1pf(__expf(-fabsf(acc)));
    delta[(size_t)(t0 + tok) * D_ + d] = sp;
  }
}

// ---------------- scan phase 1: per-chunk summaries (h0 = 0) ----------------
__global__ __launch_bounds__(256) void k_scan1(
    const float* __restrict__ x, const float* __restrict__ delta,
    const float* __restrict__ Bm, const float* __restrict__ A_log,
    float* __restrict__ aprod, float* __restrict__ hend) {
  int g = blockIdx.x * 256 + threadIdx.x;
  int d = g & (D_ - 1);
  int c = (g >> 10) & (NC - 1);
  int b = g >> 16;

  float Ad[N_];
  {
    const float4* a4 = (const float4*)(A_log + (size_t)d * N_);
    #pragma unroll
    for (int j = 0; j < 4; ++j) {
      float4 v = a4[j];
      Ad[4*j+0] = -__expf(v.x); Ad[4*j+1] = -__expf(v.y);
      Ad[4*j+2] = -__expf(v.z); Ad[4*j+3] = -__expf(v.w);
    }
  }
  float ap[N_], h[N_];
  #pragma unroll
  for (int n = 0; n < N_; ++n) { ap[n] = 1.f; h[n] = 0.f; }

  const int s0 = c * CL;
  size_t base = ((size_t)b * S_ + s0) * D_ + d;
  size_t bcb = ((size_t)b * S_ + s0) * N_;
  for (int s = 0; s < CL; ++s) {
    float dlt = delta[base + (size_t)s * D_];
    float xv  = x[base + (size_t)s * D_];
    float dbx = dlt * xv;
    const float* Brow = Bm + bcb + s * N_;
    #pragma unroll
    for (int n = 0; n < N_; ++n) {
      float da = __expf(dlt * Ad[n]);
      ap[n] *= da;
      h[n] = da * h[n] + dbx * Brow[n];
    }
  }
  size_t o = (((size_t)b * NC + c) * D_ + d) * N_;
  #pragma unroll
  for (int j = 0; j < 4; ++j) {
    *(float4*)&aprod[o + 4*j] = make_float4(ap[4*j], ap[4*j+1], ap[4*j+2], ap[4*j+3]);
    *(float4*)&hend[o + 4*j]  = make_float4(h[4*j], h[4*j+1], h[4*j+2], h[4*j+3]);
  }
}

// ---------------- scan phase 2: scan chunk summaries ----------------
__global__ __launch_bounds__(256) void k_scan2(
    const float* __restrict__ aprod, const float* __restrict__ hend,
    float* __restrict__ hstart) {
  int g = blockIdx.x * 256 + threadIdx.x;   // B_*D_*N_ = 32768 threads
  int n = g & (N_ - 1);
  int d = (g >> 4) & (D_ - 1);
  int b = g >> 14;
  float h = 0.f;
  for (int c = 0; c < NC; ++c) {
    size_t idx = (((size_t)b * NC + c) * D_ + d) * N_ + n;
    hstart[idx] = h;
    h = aprod[idx] * h + hend[idx];
  }
}

// ---------------- scan phase 3: recompute with correct h_start, emit y ----------------
__global__ __launch_bounds__(256) void k_scan3(
    const float* __restrict__ x, const float* __restrict__ delta,
    const float* __restrict__ Bm, const float* __restrict__ Cm,
    const float* __restrict__ A_log, const float* __restrict__ hstart,
    float* __restrict__ ypre) {
  int g = blockIdx.x * 256 + threadIdx.x;
  int d = g & (D_ - 1);
  int c = (g >> 10) & (NC - 1);
  int b = g >> 16;

  float Ad[N_];
  {
    const float4* a4 = (const float4*)(A_log + (size_t)d * N_);
    #pragma unroll
    for (int j = 0; j < 4; ++j) {
      float4 v = a4[j];
      Ad[4*j+0] = -__expf(v.x); Ad[4*j+1] = -__expf(v.y);
      Ad[4*j+2] = -__expf(v.z); Ad[4*j+3] = -__expf(v.w);
    }
  }
  float h[N_];
  {
    size_t o = (((size_t)b * NC + c) * D_ + d) * N_;
    #pragma unroll
    for (int j = 0; j < 4; ++j) {
      float4 v = *(const float4*)&hstart[o + 4*j];
      h[4*j] = v.x; h[4*j+1] = v.y; h[4*j+2] = v.z; h[4*j+3] = v.w;
    }
  }
  const int s0 = c * CL;
  size_t base = ((size_t)b * S_ + s0) * D_ + d;
  size_t bcb = ((size_t)b * S_ + s0) * N_;
  for (int s = 0; s < CL; ++s) {
    float dlt = delta[base + (size_t)s * D_];
    float xv  = x[base + (size_t)s * D_];
    float dbx = dlt * xv;
    const float* Brow = Bm + bcb + s * N_;
    const float* Crow = Cm + bcb + s * N_;
    float y = 0.f;
    #pragma unroll
    for (int n = 0; n < N_; ++n) {
      float da = __expf(dlt * Ad[n]);
      h[n] = da * h[n] + dbx * Brow[n];
      y += h[n] * Crow[n];
    }
    ypre[base + (size_t)s * D_] = y;
  }
}

// ---------------- residual + layernorm (in-place on ypre) ----------------
__device__ __forceinline__ float block_sum256(float v, float* sm) {
  #pragma unroll
  for (int o = 32; o > 0; o >>= 1) v += __shfl_down(v, o, 64);
  int w = threadIdx.x >> 6;
  __syncthreads();
  if ((threadIdx.x & 63) == 0) sm[w] = v;
  __syncthreads();
  return (sm[0] + sm[1]) + (sm[2] + sm[3]);
}

__global__ __launch_bounds__(256) void k_ln(
    float* __restrict__ y, const float* __restrict__ x,
    const float* __restrict__ Dp, const float* __restrict__ g,
    const float* __restrict__ bta) {
  __shared__ float sm[4];
  const int t = blockIdx.x;
  const int tid = threadIdx.x;
  size_t base = (size_t)t * D_ + tid * 4;
  float4 v = *(float4*)&y[base];
  float4 xv = *(const float4*)&x[base];
  float4 dp = *(const float4*)&Dp[tid * 4];
  v.x += dp.x * xv.x; v.y += dp.y * xv.y; v.z += dp.z * xv.z; v.w += dp.w * xv.w;
  float s1 = block_sum256(v.x + v.y + v.z + v.w, sm);
  float mu = s1 * (1.f / D_);
  float cx = v.x - mu, cy = v.y - mu, cz = v.z - mu, cw = v.w - mu;
  float s2 = block_sum256(cx*cx + cy*cy + cz*cz + cw*cw, sm);
  float rs = rsqrtf(s2 * (1.f / D_) + 1e-5f);
  float4 gg = *(const float4*)&g[tid * 4];
  float4 bb = *(const float4*)&bta[tid * 4];
  float4 o;
  o.x = cx * rs * gg.x + bb.x;
  o.y = cy * rs * gg.y + bb.y;
  o.z = cz * rs * gg.z + bb.z;
  o.w = cw * rs * gg.w + bb.w;
  *(float4*)&y[base] = o;
}

// ---------------- output GEMM: O[t][e] = sum_d Y[t][d] * W[e][d] ----------------
#define BM 64
#define BN 64
#define BK 16
__global__ __launch_bounds__(256) void k_out(
    const float* __restrict__ Y, const float* __restrict__ W,
    float* __restrict__ O) {
  __shared__ __align__(16) float As[BK][BM + 4];
  __shared__ __align__(16) float Bs[BK][BN + 4];
  const int tx = threadIdx.x & 15;
  const int ty = threadIdx.x >> 4;
  const int tm0 = blockIdx.x * BM;
  const int en0 = blockIdx.y * BN;
  float acc[4][4] = {};
  const int lin = threadIdx.x * 4;
  const int m = lin >> 4;     // 0..63
  const int kk = lin & 15;    // 0,4,8,12

  for (int k0 = 0; k0 < D_; k0 += BK) {
    float4 av = *(const float4*)&Y[(size_t)(tm0 + m) * D_ + k0 + kk];
    float4 bv = *(const float4*)&W[(size_t)(en0 + m) * D_ + k0 + kk];
    As[kk+0][m] = av.x; As[kk+1][m] = av.y; As[kk+2][m] = av.z; As[kk+3][m] = av.w;
    Bs[kk+0][m] = bv.x; Bs[kk+1][m] = bv.y; Bs[kk+2][m] = bv.z; Bs[kk+3][m] = bv.w;
    __syncthreads();
    #pragma unroll
    for (int k = 0; k < BK; ++k) {
      float a[4], b[4];
      *(float4*)a = *(const float4*)&As[k][ty * 4];
      *(float4*)b = *(const float4*)&Bs[k][tx * 4];
      #pragma unroll
      for (int i = 0; i < 4; ++i)
        #pragma unroll
        for (int j = 0; j < 4; ++j)
          acc[i][j] += a[i] * b[j];
    }
    __syncthreads();
  }
  #pragma unroll
  for (int i = 0; i < 4; ++i) {
    float4 o = make_float4(acc[i][0], acc[i][1], acc[i][2], acc[i][3]);
    *(float4*)&O[(size_t)(tm0 + ty * 4 + i) * D_ + en0 + tx * 4] = o;
  }
}

extern "C" void kernel_launch(void* const* d_in, const int* in_sizes, int n_in,
                              void* d_out, int out_size, void* d_ws, size_t ws_size,
                              hipStream_t stream) {
  const float* x     = (const float*)d_in[0];
  const float* W_dtw = (const float*)d_in[1];
  const float* W_dt  = (const float*)d_in[2];
  const float* b_dt  = (const float*)d_in[3];
  const float* A_log = (const float*)d_in[4];
  const float* W_B   = (const float*)d_in[5];
  const float* W_C   = (const float*)d_in[6];
  const float* Dp    = (const float*)d_in[7];
  const float* ln_g  = (const float*)d_in[8];
  const float* ln_b  = (const float*)d_in[9];
  const float* W_out = (const float*)d_in[10];
  float* out = (float*)d_out;

  float* ws = (float*)d_ws;                       // ~59.2 MB used
  float* delta  = ws;                             // BS_*D_   = 4194304
  float* Bm     = delta + (size_t)BS_ * D_;       // BS_*N_   = 65536
  float* Cm     = Bm + (size_t)BS_ * N_;          // BS_*N_   = 65536
  float* ypre   = Cm + (size_t)BS_ * N_;          // BS_*D_   = 4194304
  float* aprod  = ypre + (size_t)BS_ * D_;        // B*NC*D*N = 2097152
  float* hend   = aprod + (size_t)B_ * NC * D_ * N_;
  float* hstart = hend + (size_t)B_ * NC * D_ * N_;

  k_proj<<<dim3(BS_ / 8), dim3(256), 0, stream>>>(x, W_dtw, W_dt, b_dt, W_B, W_C,
                                                  delta, Bm, Cm);
  k_scan1<<<dim3(B_ * NC * D_ / 256), dim3(256), 0, stream>>>(x, delta, Bm, A_log,
                                                              aprod, hend);
  k_scan2<<<dim3(B_ * D_ * N_ / 256), dim3(256), 0, stream>>>(aprod, hend, hstart);
  k_scan3<<<dim3(B_ * NC * D_ / 256), dim3(256), 0, stream>>>(x, delta, Bm, Cm, A_log,
                                                              hstart, ypre);
  k_ln<<<dim3(BS_), dim3(256), 0, stream>>>(ypre, x, Dp, ln_g, ln_b);
  k_out<<<dim3(BS_ / BM, D_ / BN), dim3(256), 0, stream>>>(ypre, W_out, out);
}

// Round 2
// 174.146 us; speedup vs baseline: 1.8767x; 1.8767x over previous
//
#include <hip/hip_runtime.h>
#include <hip/hip_bf16.h>

#define B_ 2
#define S_ 2048
#define D_ 1024
#define N_ 16
#define R_ 64
#define NC 64          // number of scan chunks
#define CL 32          // chunk length  (NC*CL == S_)
#define BS_ (B_*S_)

typedef __attribute__((ext_vector_type(4))) float f32x4;
typedef __attribute__((ext_vector_type(8))) short bf16x8;
typedef __attribute__((ext_vector_type(8))) unsigned short u16x8;

__device__ __forceinline__ unsigned short f2b(float v) {
  unsigned u = __builtin_bit_cast(unsigned, v);
  unsigned r = ((u >> 16) & 1u) + 0x7FFFu;
  return (unsigned short)((u + r) >> 16);
}

__device__ __forceinline__ void gload_lds16(const void* g, void* l) {
  __builtin_amdgcn_global_load_lds(
      (const __attribute__((address_space(1))) unsigned int*)g,
      (__attribute__((address_space(3))) unsigned int*)l, 16, 0, 0);
}

// ---------------- generic fp32 -> bf16 cast ----------------
__global__ __launch_bounds__(256) void k_cast(const float* __restrict__ s,
                                              unsigned short* __restrict__ d, int n) {
  int i = (blockIdx.x * 256 + threadIdx.x) * 4;
  if (i >= n) return;
  float4 v = *(const float4*)&s[i];
  ushort4 o;
  o.x = f2b(v.x); o.y = f2b(v.y); o.z = f2b(v.z); o.w = f2b(v.w);
  *(ushort4*)&d[i] = o;
}

// ---------------- fused x-projection: [4096,1024] x [1024,96] ----------------
// outputs: dt (bf16, cols 0..63), Bm (fp32, cols 64..79), Cm (fp32, cols 80..95)
__global__ __launch_bounds__(256) void k_proj(
    const float* __restrict__ x, const float* __restrict__ W_dtw,
    const float* __restrict__ W_B, const float* __restrict__ W_C,
    unsigned short* __restrict__ dtb, float* __restrict__ Bm, float* __restrict__ Cm) {
  __shared__ __align__(16) unsigned short Xs[64 * 64];   // 8KB
  __shared__ __align__(16) unsigned short Ws[96 * 64];   // 12KB
  const int tid = threadIdx.x;
  const int lane = tid & 63, w = tid >> 6;
  const size_t row0 = (size_t)blockIdx.x * 64;
  f32x4 acc[6] = {};

  for (int k0 = 0; k0 < D_; k0 += 64) {
    // stage x tile 64x64 (fp32 -> bf16, swizzled LDS write)
    #pragma unroll
    for (int i = 0; i < 2; ++i) {
      int id = i * 256 + tid;
      int row = id >> 3, s = id & 7;
      const float* gp = &x[(row0 + row) * D_ + k0 + s * 8];
      float4 v0 = *(const float4*)gp;
      float4 v1 = *(const float4*)(gp + 4);
      u16x8 u;
      u[0] = f2b(v0.x); u[1] = f2b(v0.y); u[2] = f2b(v0.z); u[3] = f2b(v0.w);
      u[4] = f2b(v1.x); u[5] = f2b(v1.y); u[6] = f2b(v1.z); u[7] = f2b(v1.w);
      *(u16x8*)&Xs[row * 64 + (s ^ (row & 7)) * 8] = u;
    }
    // stage W tile 96x64
    #pragma unroll
    for (int i = 0; i < 3; ++i) {
      int id = i * 256 + tid;
      int row = id >> 3, s = id & 7;
      const float* wrow = (row < 64) ? (W_dtw + (size_t)row * D_)
                        : (row < 80) ? (W_B + (size_t)(row - 64) * D_)
                                     : (W_C + (size_t)(row - 80) * D_);
      const float* gp = wrow + k0 + s * 8;
      float4 v0 = *(const float4*)gp;
      float4 v1 = *(const float4*)(gp + 4);
      u16x8 u;
      u[0] = f2b(v0.x); u[1] = f2b(v0.y); u[2] = f2b(v0.z); u[3] = f2b(v0.w);
      u[4] = f2b(v1.x); u[5] = f2b(v1.y); u[6] = f2b(v1.z); u[7] = f2b(v1.w);
      *(u16x8*)&Ws[row * 64 + (s ^ (row & 7)) * 8] = u;
    }
    __syncthreads();
    const int r = lane & 15, kg = lane >> 4;
    #pragma unroll
    for (int ks = 0; ks < 2; ++ks) {
      const int arow = w * 16 + r;
      bf16x8 a = *(const bf16x8*)&Xs[arow * 64 + (((ks << 2) | kg) ^ (arow & 7)) * 8];
      #pragma unroll
      for (int nt = 0; nt < 6; ++nt) {
        const int brow = nt * 16 + r;
        bf16x8 b = *(const bf16x8*)&Ws[brow * 64 + (((ks << 2) | kg) ^ (brow & 7)) * 8];
        acc[nt] = __builtin_amdgcn_mfma_f32_16x16x32_bf16(a, b, acc[nt], 0, 0, 0);
      }
    }
    __syncthreads();
  }
  const int cr = lane >> 4, cc = lane & 15;
  #pragma unroll
  for (int nt = 0; nt < 6; ++nt) {
    #pragma unroll
    for (int j = 0; j < 4; ++j) {
      size_t trow = row0 + w * 16 + cr * 4 + j;
      float v = acc[nt][j];
      if (nt < 4)      dtb[trow * R_ + nt * 16 + cc] = f2b(v);
      else if (nt == 4) Bm[trow * N_ + cc] = v;
      else              Cm[trow * N_ + cc] = v;
    }
  }
}

// ---------------- delta GEMM: softplus(dt[4096,64] x W_dt^T[64,1024] + b) ----------------
__global__ __launch_bounds__(256) void k_delta(
    const unsigned short* __restrict__ dtb, const unsigned short* __restrict__ wdtb,
    const float* __restrict__ b_dt, float* __restrict__ delta) {
  __shared__ __align__(16) unsigned short As[128 * 64];  // 16KB
  __shared__ __align__(16) unsigned short Bs[128 * 64];  // 16KB
  const int tid = threadIdx.x;
  const int lane = tid & 63, wid = tid >> 6;
  const int wr = wid >> 1, wc = wid & 1;
  const size_t row0 = (size_t)blockIdx.x * 128;
  const size_t col0 = (size_t)blockIdx.y * 128;
  f32x4 acc[4][4] = {};

  {
    const int r = tid >> 3, s = tid & 7;
    #pragma unroll
    for (int i = 0; i < 4; ++i) {
      const int row = i * 32 + r;
      const int gs = s ^ (row & 7);
      gload_lds16(dtb + (row0 + row) * R_ + gs * 8, As + row * 64 + s * 8);
      gload_lds16(wdtb + (col0 + row) * R_ + gs * 8, Bs + row * 64 + s * 8);
    }
  }
  __syncthreads();
  const int r = lane & 15, kg = lane >> 4;
  #pragma unroll
  for (int ks = 0; ks < 2; ++ks) {
    bf16x8 a[4], b[4];
    #pragma unroll
    for (int m = 0; m < 4; ++m) {
      const int arow = wr * 64 + m * 16 + r;
      a[m] = *(const bf16x8*)&As[arow * 64 + (((ks << 2) | kg) ^ (arow & 7)) * 8];
    }
    #pragma unroll
    for (int n = 0; n < 4; ++n) {
      const int brow = wc * 64 + n * 16 + r;
      b[n] = *(const bf16x8*)&Bs[brow * 64 + (((ks << 2) | kg) ^ (brow & 7)) * 8];
    }
    #pragma unroll
    for (int m = 0; m < 4; ++m)
      #pragma unroll
      for (int n = 0; n < 4; ++n)
        acc[m][n] = __builtin_amdgcn_mfma_f32_16x16x32_bf16(a[m], b[n], acc[m][n], 0, 0, 0);
  }
  const int cr = lane >> 4, cc = lane & 15;
  #pragma unroll
  for (int m = 0; m < 4; ++m) {
    #pragma unroll
    for (int n = 0; n < 4; ++n) {
      const int d = (int)col0 + wc * 64 + n * 16 + cc;
      const float bd = b_dt[d];
      #pragma unroll
      for (int j = 0; j < 4; ++j) {
        size_t trow = row0 + wr * 64 + m * 16 + cr * 4 + j;
        float v = acc[m][n][j] + bd;
        float sp = fmaxf(v, 0.f) + log1pf(__expf(-fabsf(v)));
        delta[trow * D_ + d] = sp;
      }
    }
  }
}

// ---------------- scan phase 1: per-chunk summaries (h0 = 0) ----------------
__global__ __launch_bounds__(256) void k_scan1(
    const float* __restrict__ x, const float* __restrict__ delta,
    const float* __restrict__ Bm, const float* __restrict__ A_log,
    float* __restrict__ aprod, float* __restrict__ hend) {
  int g = blockIdx.x * 256 + threadIdx.x;
  int d = g & (D_ - 1);
  int c = (g >> 10) & (NC - 1);
  int b = g >> 16;

  float Ad[N_];
  {
    const float4* a4 = (const float4*)(A_log + (size_t)d * N_);
    #pragma unroll
    for (int j = 0; j < 4; ++j) {
      float4 v = a4[j];
      Ad[4*j+0] = -__expf(v.x); Ad[4*j+1] = -__expf(v.y);
      Ad[4*j+2] = -__expf(v.z); Ad[4*j+3] = -__expf(v.w);
    }
  }
  float ap[N_], h[N_];
  #pragma unroll
  for (int n = 0; n < N_; ++n) { ap[n] = 1.f; h[n] = 0.f; }

  const int s0 = c * CL;
  size_t base = ((size_t)b * S_ + s0) * D_ + d;
  size_t bcb = ((size_t)b * S_ + s0) * N_;
  for (int s = 0; s < CL; ++s) {
    float dlt = delta[base + (size_t)s * D_];
    float xv  = x[base + (size_t)s * D_];
    float dbx = dlt * xv;
    const float* Brow = Bm + bcb + s * N_;
    #pragma unroll
    for (int n = 0; n < N_; ++n) {
      float da = __expf(dlt * Ad[n]);
      ap[n] *= da;
      h[n] = da * h[n] + dbx * Brow[n];
    }
  }
  size_t o = (((size_t)b * NC + c) * D_ + d) * N_;
  #pragma unroll
  for (int j = 0; j < 4; ++j) {
    *(float4*)&aprod[o + 4*j] = make_float4(ap[4*j], ap[4*j+1], ap[4*j+2], ap[4*j+3]);
    *(float4*)&hend[o + 4*j]  = make_float4(h[4*j], h[4*j+1], h[4*j+2], h[4*j+3]);
  }
}

// ---------------- scan phase 2: scan chunk summaries ----------------
__global__ __launch_bounds__(256) void k_scan2(
    const float* __restrict__ aprod, const float* __restrict__ hend,
    float* __restrict__ hstart) {
  int g = blockIdx.x * 256 + threadIdx.x;   // B_*D_*N_ = 32768 threads
  int n = g & (N_ - 1);
  int d = (g >> 4) & (D_ - 1);
  int b = g >> 14;
  float h = 0.f;
  for (int c = 0; c < NC; ++c) {
    size_t idx = (((size_t)b * NC + c) * D_ + d) * N_ + n;
    hstart[idx] = h;
    h = aprod[idx] * h + hend[idx];
  }
}

// ---------------- scan phase 3: recompute with correct h_start, emit y ----------------
__global__ __launch_bounds__(256) void k_scan3(
    const float* __restrict__ x, const float* __restrict__ delta,
    const float* __restrict__ Bm, const float* __restrict__ Cm,
    const float* __restrict__ A_log, const float* __restrict__ hstart,
    float* __restrict__ ypre) {
  int g = blockIdx.x * 256 + threadIdx.x;
  int d = g & (D_ - 1);
  int c = (g >> 10) & (NC - 1);
  int b = g >> 16;

  float Ad[N_];
  {
    const float4* a4 = (const float4*)(A_log + (size_t)d * N_);
    #pragma unroll
    for (int j = 0; j < 4; ++j) {
      float4 v = a4[j];
      Ad[4*j+0] = -__expf(v.x); Ad[4*j+1] = -__expf(v.y);
      Ad[4*j+2] = -__expf(v.z); Ad[4*j+3] = -__expf(v.w);
    }
  }
  float h[N_];
  {
    size_t o = (((size_t)b * NC + c) * D_ + d) * N_;
    #pragma unroll
    for (int j = 0; j < 4; ++j) {
      float4 v = *(const float4*)&hstart[o + 4*j];
      h[4*j] = v.x; h[4*j+1] = v.y; h[4*j+2] = v.z; h[4*j+3] = v.w;
    }
  }
  const int s0 = c * CL;
  size_t base = ((size_t)b * S_ + s0) * D_ + d;
  size_t bcb = ((size_t)b * S_ + s0) * N_;
  for (int s = 0; s < CL; ++s) {
    float dlt = delta[base + (size_t)s * D_];
    float xv  = x[base + (size_t)s * D_];
    float dbx = dlt * xv;
    const float* Brow = Bm + bcb + s * N_;
    const float* Crow = Cm + bcb + s * N_;
    float y = 0.f;
    #pragma unroll
    for (int n = 0; n < N_; ++n) {
      float da = __expf(dlt * Ad[n]);
      h[n] = da * h[n] + dbx * Brow[n];
      y += h[n] * Crow[n];
    }
    ypre[base + (size_t)s * D_] = y;
  }
}

// ---------------- residual + layernorm -> bf16 y ----------------
__device__ __forceinline__ float block_sum256(float v, float* sm) {
  #pragma unroll
  for (int o = 32; o > 0; o >>= 1) v += __shfl_down(v, o, 64);
  int w = threadIdx.x >> 6;
  __syncthreads();
  if ((threadIdx.x & 63) == 0) sm[w] = v;
  __syncthreads();
  return (sm[0] + sm[1]) + (sm[2] + sm[3]);
}

__global__ __launch_bounds__(256) void k_ln(
    const float* __restrict__ ypre, const float* __restrict__ x,
    const float* __restrict__ Dp, const float* __restrict__ g,
    const float* __restrict__ bta, unsigned short* __restrict__ ybf) {
  __shared__ float sm[4];
  const int t = blockIdx.x;
  const int tid = threadIdx.x;
  size_t base = (size_t)t * D_ + tid * 4;
  float4 v = *(const float4*)&ypre[base];
  float4 xv = *(const float4*)&x[base];
  float4 dp = *(const float4*)&Dp[tid * 4];
  v.x += dp.x * xv.x; v.y += dp.y * xv.y; v.z += dp.z * xv.z; v.w += dp.w * xv.w;
  float s1 = block_sum256(v.x + v.y + v.z + v.w, sm);
  float mu = s1 * (1.f / D_);
  float cx = v.x - mu, cy = v.y - mu, cz = v.z - mu, cw = v.w - mu;
  float s2 = block_sum256(cx*cx + cy*cy + cz*cz + cw*cw, sm);
  float rs = rsqrtf(s2 * (1.f / D_) + 1e-5f);
  float4 gg = *(const float4*)&g[tid * 4];
  float4 bb = *(const float4*)&bta[tid * 4];
  ushort4 o;
  o.x = f2b(cx * rs * gg.x + bb.x);
  o.y = f2b(cy * rs * gg.y + bb.y);
  o.z = f2b(cz * rs * gg.z + bb.z);
  o.w = f2b(cw * rs * gg.w + bb.w);
  *(ushort4*)&ybf[base] = o;
}

// ---------------- output GEMM: O = Y[4096,1024] x W_out^T, bf16 MFMA ----------------
__device__ __forceinline__ void stage128x64(const unsigned short* __restrict__ g,
                                            size_t row0, int k0,
                                            unsigned short* lds, int tid) {
  const int r = tid >> 3, s = tid & 7;
  #pragma unroll
  for (int i = 0; i < 4; ++i) {
    const int row = i * 32 + r;
    const int gs = s ^ (row & 7);
    gload_lds16(g + ((row0 + row) << 10) + k0 + (gs << 3), lds + row * 64 + s * 8);
  }
}

__global__ __launch_bounds__(256) void k_out(const unsigned short* __restrict__ Y,
                                             const unsigned short* __restrict__ W,
                                             float* __restrict__ O) {
  __shared__ __align__(16) unsigned short As[2][128 * 64];  // 2x16KB
  __shared__ __align__(16) unsigned short Bs[2][128 * 64];
  const int tid = threadIdx.x;
  const int lane = tid & 63, wid = tid >> 6;
  const int wr = wid >> 1, wc = wid & 1;
  const size_t row0 = (size_t)blockIdx.x * 128;
  const size_t col0 = (size_t)blockIdx.y * 128;
  f32x4 acc[4][4] = {};

  stage128x64(Y, row0, 0, As[0], tid);
  stage128x64(W, col0, 0, Bs[0], tid);
  __syncthreads();

  int cur = 0;
  const int r = lane & 15, kg = lane >> 4;
  for (int t = 0; t < 16; ++t) {
    if (t + 1 < 16) {
      stage128x64(Y, row0, (t + 1) * 64, As[cur ^ 1], tid);
      stage128x64(W, col0, (t + 1) * 64, Bs[cur ^ 1], tid);
    }
    #pragma unroll
    for (int ks = 0; ks < 2; ++ks) {
      bf16x8 a[4], b[4];
      #pragma unroll
      for (int m = 0; m < 4; ++m) {
        const int arow = wr * 64 + m * 16 + r;
        a[m] = *(const bf16x8*)&As[cur][arow * 64 + (((ks << 2) | kg) ^ (arow & 7)) * 8];
      }
      #pragma unroll
      for (int n = 0; n < 4; ++n) {
        const int brow = wc * 64 + n * 16 + r;
        b[n] = *(const bf16x8*)&Bs[cur][brow * 64 + (((ks << 2) | kg) ^ (brow & 7)) * 8];
      }
      #pragma unroll
      for (int m = 0; m < 4; ++m)
        #pragma unroll
        for (int n = 0; n < 4; ++n)
          acc[m][n] = __builtin_amdgcn_mfma_f32_16x16x32_bf16(a[m], b[n], acc[m][n], 0, 0, 0);
    }
    __syncthreads();   // drains vmcnt(0): next buffer ready; all waves done with cur
    cur ^= 1;
  }

  const int cr = lane >> 4, cc = lane & 15;
  #pragma unroll
  for (int m = 0; m < 4; ++m) {
    #pragma unroll
    for (int n = 0; n < 4; ++n) {
      size_t orow = row0 + wr * 64 + m * 16 + cr * 4;
      float* op = O + orow * D_ + col0 + wc * 64 + n * 16 + cc;
      #pragma unroll
      for (int j = 0; j < 4; ++j) op[(size_t)j * D_] = acc[m][n][j];
    }
  }
}

extern "C" void kernel_launch(void* const* d_in, const int* in_sizes, int n_in,
                              void* d_out, int out_size, void* d_ws, size_t ws_size,
                              hipStream_t stream) {
  const float* x     = (const float*)d_in[0];
  const float* W_dtw = (const float*)d_in[1];
  const float* W_dt  = (const float*)d_in[2];
  const float* b_dt  = (const float*)d_in[3];
  const float* A_log = (const float*)d_in[4];
  const float* W_B   = (const float*)d_in[5];
  const float* W_C   = (const float*)d_in[6];
  const float* Dp    = (const float*)d_in[7];
  const float* ln_g  = (const float*)d_in[8];
  const float* ln_b  = (const float*)d_in[9];
  const float* W_out = (const float*)d_in[10];
  float* out = (float*)d_out;

  float* ws = (float*)d_ws;                       // 59.2 MB total (same as round 1)
  float* delta  = ws;                             // BS_*D_   = 4194304
  float* Bm     = delta + (size_t)BS_ * D_;       // 65536
  float* Cm     = Bm + (size_t)BS_ * N_;          // 65536
  float* ypre   = Cm + (size_t)BS_ * N_;          // 4194304
  float* aprod  = ypre + (size_t)BS_ * D_;        // 2097152
  float* hend   = aprod + (size_t)B_ * NC * D_ * N_;   // 2097152
  float* hstart = hend + (size_t)B_ * NC * D_ * N_;    // 2097152
  // lifetime-disjoint overlays:
  unsigned short* dtb  = (unsigned short*)hstart;          // 262144 u16 (dead before scan2)
  unsigned short* wdtb = dtb + (size_t)BS_ * R_;           // 65536 u16
  unsigned short* ybf  = (unsigned short*)aprod;           // 4194304 u16 (after scan2)
  unsigned short* wob  = (unsigned short*)hend;            // 1048576 u16 (after scan2)

  k_cast<<<dim3(64), dim3(256), 0, stream>>>(W_dt, wdtb, D_ * R_);
  k_proj<<<dim3(BS_ / 64), dim3(256), 0, stream>>>(x, W_dtw, W_B, W_C, dtb, Bm, Cm);
  k_delta<<<dim3(BS_ / 128, D_ / 128), dim3(256), 0, stream>>>(dtb, wdtb, b_dt, delta);
  k_scan1<<<dim3(B_ * NC * D_ / 256), dim3(256), 0, stream>>>(x, delta, Bm, A_log,
                                                              aprod, hend);
  k_scan2<<<dim3(B_ * D_ * N_ / 256), dim3(256), 0, stream>>>(aprod, hend, hstart);
  k_cast<<<dim3(1024), dim3(256), 0, stream>>>(W_out, wob, D_ * D_);
  k_scan3<<<dim3(B_ * NC * D_ / 256), dim3(256), 0, stream>>>(x, delta, Bm, Cm, A_log,
                                                              hstart, ypre);
  k_ln<<<dim3(BS_), dim3(256), 0, stream>>>(ypre, x, Dp, ln_g, ln_b, ybf);
  k_out<<<dim3(BS_ / 128, D_ / 128), dim3(256), 0, stream>>>(ybf, wob, out);
}

// Round 3
// 129.603 us; speedup vs baseline: 2.5217x; 1.3437x over previous
//
#include <hip/hip_runtime.h>
#include <hip/hip_bf16.h>

#define B_ 2
#define S_ 2048
#define D_ 1024
#define N_ 16
#define R_ 64
#define NC 64          // number of scan chunks
#define CL 32          // chunk length  (NC*CL == S_)
#define BS_ (B_*S_)

typedef __attribute__((ext_vector_type(4))) float f32x4;
typedef __attribute__((ext_vector_type(8))) short bf16x8;
typedef __attribute__((ext_vector_type(8))) unsigned short u16x8;

__device__ __forceinline__ unsigned short f2b(float v) {
  unsigned u = __builtin_bit_cast(unsigned, v);
  unsigned r = ((u >> 16) & 1u) + 0x7FFFu;
  return (unsigned short)((u + r) >> 16);
}

__device__ __forceinline__ void gload_lds16(const void* g, void* l) {
  __builtin_amdgcn_global_load_lds(
      (const __attribute__((address_space(1))) unsigned int*)g,
      (__attribute__((address_space(3))) unsigned int*)l, 16, 0, 0);
}

// ---------------- generic fp32 -> bf16 cast ----------------
__global__ __launch_bounds__(256) void k_cast(const float* __restrict__ s,
                                              unsigned short* __restrict__ d, int n) {
  int i = (blockIdx.x * 256 + threadIdx.x) * 4;
  if (i >= n) return;
  float4 v = *(const float4*)&s[i];
  ushort4 o;
  o.x = f2b(v.x); o.y = f2b(v.y); o.z = f2b(v.z); o.w = f2b(v.w);
  *(ushort4*)&d[i] = o;
}

// ---------------- fused x-projection GEMM, K-split by 4 ----------------
// [4096,1024] x [1024,96] -> fp32 partials part[ksplit][4096][96]
__global__ __launch_bounds__(256) void k_proj(
    const unsigned short* __restrict__ xb, const unsigned short* __restrict__ Wcat,
    float* __restrict__ part) {
  __shared__ __align__(16) unsigned short Xs[2][64 * 64];   // 2x8KB
  __shared__ __align__(16) unsigned short Ws[2][96 * 64];   // 2x12KB
  const int tid = threadIdx.x;
  const int lane = tid & 63, w = tid >> 6;
  const size_t row0 = (size_t)blockIdx.x * 64;
  const int kbase = blockIdx.y * 256;
  f32x4 acc[6] = {};

  auto stage = [&](int buf, int k0) {
    #pragma unroll
    for (int i = 0; i < 2; ++i) {
      int id = i * 256 + tid; int row = id >> 3, s = id & 7;
      gload_lds16(xb + (row0 + row) * D_ + k0 + ((s ^ (row & 7)) << 3),
                  Xs[buf] + row * 64 + s * 8);
    }
    #pragma unroll
    for (int i = 0; i < 3; ++i) {
      int id = i * 256 + tid; int row = id >> 3, s = id & 7;
      gload_lds16(Wcat + (size_t)row * D_ + k0 + ((s ^ (row & 7)) << 3),
                  Ws[buf] + row * 64 + s * 8);
    }
  };
  stage(0, kbase);
  __syncthreads();
  int cur = 0;
  const int r = lane & 15, kg = lane >> 4;
  for (int t = 0; t < 4; ++t) {
    if (t < 3) stage(cur ^ 1, kbase + (t + 1) * 64);
    #pragma unroll
    for (int ks = 0; ks < 2; ++ks) {
      const int arow = w * 16 + r;
      bf16x8 a = *(const bf16x8*)&Xs[cur][arow * 64 + ((((ks << 2) | kg) ^ (arow & 7)) << 3)];
      #pragma unroll
      for (int nt = 0; nt < 6; ++nt) {
        const int brow = nt * 16 + r;
        bf16x8 b = *(const bf16x8*)&Ws[cur][brow * 64 + ((((ks << 2) | kg) ^ (brow & 7)) << 3)];
        acc[nt] = __builtin_amdgcn_mfma_f32_16x16x32_bf16(a, b, acc[nt], 0, 0, 0);
      }
    }
    __syncthreads();
    cur ^= 1;
  }
  const int cr = lane >> 4, cc = lane & 15;
  float* pb = part + (size_t)blockIdx.y * (BS_ * 96);
  #pragma unroll
  for (int nt = 0; nt < 6; ++nt)
    #pragma unroll
    for (int j = 0; j < 4; ++j)
      pb[(row0 + w * 16 + cr * 4 + j) * 96 + nt * 16 + cc] = acc[nt][j];
}

// reduce 4 K-split partials -> dtb (bf16), Bm, Cm (fp32)
__global__ __launch_bounds__(256) void k_projred(
    const float* __restrict__ part, unsigned short* __restrict__ dtb,
    float* __restrict__ Bm, float* __restrict__ Cm) {
  int e = blockIdx.x * 256 + threadIdx.x;        // < 4096*96
  int row = e / 96, col = e - row * 96;
  float s = part[e] + part[e + BS_ * 96] + part[e + 2 * BS_ * 96] + part[e + 3 * BS_ * 96];
  if (col < 64)      dtb[row * R_ + col] = f2b(s);
  else if (col < 80) Bm[row * N_ + col - 64] = s;
  else               Cm[row * N_ + col - 80] = s;
}

// ---------------- delta GEMM: softplus(dt[4096,64] x W_dt^T[64,1024] + b) ----------------
__global__ __launch_bounds__(256) void k_delta(
    const unsigned short* __restrict__ dtb, const unsigned short* __restrict__ wdtb,
    const float* __restrict__ b_dt, float* __restrict__ delta) {
  __shared__ __align__(16) unsigned short As[128 * 64];  // 16KB
  __shared__ __align__(16) unsigned short Bs[128 * 64];  // 16KB
  const int tid = threadIdx.x;
  const int lane = tid & 63, wid = tid >> 6;
  const int wr = wid >> 1, wc = wid & 1;
  const size_t row0 = (size_t)blockIdx.x * 128;
  const size_t col0 = (size_t)blockIdx.y * 128;
  f32x4 acc[4][4] = {};

  {
    const int r = tid >> 3, s = tid & 7;
    #pragma unroll
    for (int i = 0; i < 4; ++i) {
      const int row = i * 32 + r;
      const int gs = s ^ (row & 7);
      gload_lds16(dtb + (row0 + row) * R_ + gs * 8, As + row * 64 + s * 8);
      gload_lds16(wdtb + (col0 + row) * R_ + gs * 8, Bs + row * 64 + s * 8);
    }
  }
  __syncthreads();
  const int r = lane & 15, kg = lane >> 4;
  #pragma unroll
  for (int ks = 0; ks < 2; ++ks) {
    bf16x8 a[4], b[4];
    #pragma unroll
    for (int m = 0; m < 4; ++m) {
      const int arow = wr * 64 + m * 16 + r;
      a[m] = *(const bf16x8*)&As[arow * 64 + (((ks << 2) | kg) ^ (arow & 7)) * 8];
    }
    #pragma unroll
    for (int n = 0; n < 4; ++n) {
      const int brow = wc * 64 + n * 16 + r;
      b[n] = *(const bf16x8*)&Bs[brow * 64 + (((ks << 2) | kg) ^ (brow & 7)) * 8];
    }
    #pragma unroll
    for (int m = 0; m < 4; ++m)
      #pragma unroll
      for (int n = 0; n < 4; ++n)
        acc[m][n] = __builtin_amdgcn_mfma_f32_16x16x32_bf16(a[m], b[n], acc[m][n], 0, 0, 0);
  }
  const int cr = lane >> 4, cc = lane & 15;
  #pragma unroll
  for (int m = 0; m < 4; ++m) {
    #pragma unroll
    for (int n = 0; n < 4; ++n) {
      const int d = (int)col0 + wc * 64 + n * 16 + cc;
      const float bd = b_dt[d];
      #pragma unroll
      for (int j = 0; j < 4; ++j) {
        size_t trow = row0 + wr * 64 + m * 16 + cr * 4 + j;
        float v = acc[m][n][j] + bd;
        float sp = fmaxf(v, 0.f) + log1pf(__expf(-fabsf(v)));
        delta[trow * D_ + d] = sp;
      }
    }
  }
}

// ---------------- scan phase 1: per-chunk summaries, 4 lanes per d ----------------
__global__ __launch_bounds__(256) void k_scan1(
    const float* __restrict__ x, const float* __restrict__ delta,
    const float* __restrict__ Bm, const float* __restrict__ A_log,
    float* __restrict__ aprod, float* __restrict__ hend) {
  int g = blockIdx.x * 256 + threadIdx.x;     // B*NC*D*4 = 524288 threads
  int nq = g & 3;
  int d = (g >> 2) & (D_ - 1);
  int c = (g >> 12) & (NC - 1);
  int b = g >> 18;

  float4 av = *(const float4*)&A_log[(size_t)d * N_ + nq * 4];
  float Ad[4] = {-__expf(av.x), -__expf(av.y), -__expf(av.z), -__expf(av.w)};
  float ap[4] = {1.f, 1.f, 1.f, 1.f}, h[4] = {0.f, 0.f, 0.f, 0.f};

  size_t base = (size_t)(b * S_ + c * CL) * D_ + d;
  size_t bcb  = (size_t)(b * S_ + c * CL) * N_ + nq * 4;
  for (int s = 0; s < CL; ++s) {
    float dlt = delta[base + (size_t)s * D_];
    float xv  = x[base + (size_t)s * D_];
    float dbx = dlt * xv;
    float4 Bv = *(const float4*)&Bm[bcb + (size_t)s * N_];
    float da0 = __expf(dlt * Ad[0]), da1 = __expf(dlt * Ad[1]);
    float da2 = __expf(dlt * Ad[2]), da3 = __expf(dlt * Ad[3]);
    ap[0] *= da0; ap[1] *= da1; ap[2] *= da2; ap[3] *= da3;
    h[0] = da0 * h[0] + dbx * Bv.x;
    h[1] = da1 * h[1] + dbx * Bv.y;
    h[2] = da2 * h[2] + dbx * Bv.z;
    h[3] = da3 * h[3] + dbx * Bv.w;
  }
  size_t o = (((size_t)(b * NC + c)) * D_ + d) * N_ + nq * 4;
  *(float4*)&aprod[o] = make_float4(ap[0], ap[1], ap[2], ap[3]);
  *(float4*)&hend[o]  = make_float4(h[0], h[1], h[2], h[3]);
}

// ---------------- scan phase 2: scan chunk summaries ----------------
__global__ __launch_bounds__(256) void k_scan2(
    const float* __restrict__ aprod, const float* __restrict__ hend,
    float* __restrict__ hstart) {
  int g = blockIdx.x * 256 + threadIdx.x;   // B_*D_*N_ = 32768 threads
  int n = g & (N_ - 1);
  int d = (g >> 4) & (D_ - 1);
  int b = g >> 14;
  float h = 0.f;
  for (int c = 0; c < NC; ++c) {
    size_t idx = (((size_t)b * NC + c) * D_ + d) * N_ + n;
    hstart[idx] = h;
    h = aprod[idx] * h + hend[idx];
  }
}

// ---------------- scan phase 3: recompute + y + fused residual ----------------
__global__ __launch_bounds__(256) void k_scan3(
    const float* __restrict__ x, const float* __restrict__ delta,
    const float* __restrict__ Bm, const float* __restrict__ Cm,
    const float* __restrict__ A_log, const float* __restrict__ hstart,
    const float* __restrict__ Dp, float* __restrict__ ypre) {
  int g = blockIdx.x * 256 + threadIdx.x;
  int nq = g & 3;
  int d = (g >> 2) & (D_ - 1);
  int c = (g >> 12) & (NC - 1);
  int b = g >> 18;

  float4 av = *(const float4*)&A_log[(size_t)d * N_ + nq * 4];
  float Ad[4] = {-__expf(av.x), -__expf(av.y), -__expf(av.z), -__expf(av.w)};
  float h[4];
  {
    size_t o = (((size_t)(b * NC + c)) * D_ + d) * N_ + nq * 4;
    float4 v = *(const float4*)&hstart[o];
    h[0] = v.x; h[1] = v.y; h[2] = v.z; h[3] = v.w;
  }
  const float Dpd = Dp[d];

  size_t base = (size_t)(b * S_ + c * CL) * D_ + d;
  size_t bcb  = (size_t)(b * S_ + c * CL) * N_ + nq * 4;
  for (int s = 0; s < CL; ++s) {
    float dlt = delta[base + (size_t)s * D_];
    float xv  = x[base + (size_t)s * D_];
    float dbx = dlt * xv;
    float4 Bv = *(const float4*)&Bm[bcb + (size_t)s * N_];
    float4 Cv = *(const float4*)&Cm[bcb + (size_t)s * N_];
    float da0 = __expf(dlt * Ad[0]), da1 = __expf(dlt * Ad[1]);
    float da2 = __expf(dlt * Ad[2]), da3 = __expf(dlt * Ad[3]);
    h[0] = da0 * h[0] + dbx * Bv.x;
    h[1] = da1 * h[1] + dbx * Bv.y;
    h[2] = da2 * h[2] + dbx * Bv.z;
    h[3] = da3 * h[3] + dbx * Bv.w;
    float y = h[0] * Cv.x + h[1] * Cv.y + h[2] * Cv.z + h[3] * Cv.w;
    y += __shfl_xor(y, 1);
    y += __shfl_xor(y, 2);
    if (nq == 0) ypre[base + (size_t)s * D_] = y + Dpd * xv;
  }
}

// ---------------- layernorm (residual already fused) -> bf16 y ----------------
__device__ __forceinline__ float block_sum256(float v, float* sm) {
  #pragma unroll
  for (int o = 32; o > 0; o >>= 1) v += __shfl_down(v, o, 64);
  int w = threadIdx.x >> 6;
  __syncthreads();
  if ((threadIdx.x & 63) == 0) sm[w] = v;
  __syncthreads();
  return (sm[0] + sm[1]) + (sm[2] + sm[3]);
}

__global__ __launch_bounds__(256) void k_ln(
    const float* __restrict__ ypre, const float* __restrict__ g,
    const float* __restrict__ bta, unsigned short* __restrict__ ybf) {
  __shared__ float sm[4];
  const int t = blockIdx.x;
  const int tid = threadIdx.x;
  size_t base = (size_t)t * D_ + tid * 4;
  float4 v = *(const float4*)&ypre[base];
  float s1 = block_sum256(v.x + v.y + v.z + v.w, sm);
  float mu = s1 * (1.f / D_);
  float cx = v.x - mu, cy = v.y - mu, cz = v.z - mu, cw = v.w - mu;
  float s2 = block_sum256(cx*cx + cy*cy + cz*cz + cw*cw, sm);
  float rs = rsqrtf(s2 * (1.f / D_) + 1e-5f);
  float4 gg = *(const float4*)&g[tid * 4];
  float4 bb = *(const float4*)&bta[tid * 4];
  ushort4 o;
  o.x = f2b(cx * rs * gg.x + bb.x);
  o.y = f2b(cy * rs * gg.y + bb.y);
  o.z = f2b(cz * rs * gg.z + bb.z);
  o.w = f2b(cw * rs * gg.w + bb.w);
  *(ushort4*)&ybf[base] = o;
}

// ---------------- output GEMM: O = Y[4096,1024] x W_out^T, bf16 MFMA ----------------
__device__ __forceinline__ void stage128x64(const unsigned short* __restrict__ g,
                                            size_t row0, int k0,
                                            unsigned short* lds, int tid) {
  const int r = tid >> 3, s = tid & 7;
  #pragma unroll
  for (int i = 0; i < 4; ++i) {
    const int row = i * 32 + r;
    const int gs = s ^ (row & 7);
    gload_lds16(g + ((row0 + row) << 10) + k0 + (gs << 3), lds + row * 64 + s * 8);
  }
}

__global__ __launch_bounds__(256) void k_out(const unsigned short* __restrict__ Y,
                                             const unsigned short* __restrict__ W,
                                             float* __restrict__ O) {
  __shared__ __align__(16) unsigned short As[2][128 * 64];  // 2x16KB
  __shared__ __align__(16) unsigned short Bs[2][128 * 64];
  const int tid = threadIdx.x;
  const int lane = tid & 63, wid = tid >> 6;
  const int wr = wid >> 1, wc = wid & 1;
  const size_t row0 = (size_t)blockIdx.x * 128;
  const size_t col0 = (size_t)blockIdx.y * 128;
  f32x4 acc[4][4] = {};

  stage128x64(Y, row0, 0, As[0], tid);
  stage128x64(W, col0, 0, Bs[0], tid);
  __syncthreads();

  int cur = 0;
  const int r = lane & 15, kg = lane >> 4;
  for (int t = 0; t < 16; ++t) {
    if (t + 1 < 16) {
      stage128x64(Y, row0, (t + 1) * 64, As[cur ^ 1], tid);
      stage128x64(W, col0, (t + 1) * 64, Bs[cur ^ 1], tid);
    }
    #pragma unroll
    for (int ks = 0; ks < 2; ++ks) {
      bf16x8 a[4], b[4];
      #pragma unroll
      for (int m = 0; m < 4; ++m) {
        const int arow = wr * 64 + m * 16 + r;
        a[m] = *(const bf16x8*)&As[cur][arow * 64 + (((ks << 2) | kg) ^ (arow & 7)) * 8];
      }
      #pragma unroll
      for (int n = 0; n < 4; ++n) {
        const int brow = wc * 64 + n * 16 + r;
        b[n] = *(const bf16x8*)&Bs[cur][brow * 64 + (((ks << 2) | kg) ^ (brow & 7)) * 8];
      }
      #pragma unroll
      for (int m = 0; m < 4; ++m)
        #pragma unroll
        for (int n = 0; n < 4; ++n)
          acc[m][n] = __builtin_amdgcn_mfma_f32_16x16x32_bf16(a[m], b[n], acc[m][n], 0, 0, 0);
    }
    __syncthreads();
    cur ^= 1;
  }

  const int cr = lane >> 4, cc = lane & 15;
  #pragma unroll
  for (int m = 0; m < 4; ++m) {
    #pragma unroll
    for (int n = 0; n < 4; ++n) {
      size_t orow = row0 + wr * 64 + m * 16 + cr * 4;
      float* op = O + orow * D_ + col0 + wc * 64 + n * 16 + cc;
      #pragma unroll
      for (int j = 0; j < 4; ++j) op[(size_t)j * D_] = acc[m][n][j];
    }
  }
}

extern "C" void kernel_launch(void* const* d_in, const int* in_sizes, int n_in,
                              void* d_out, int out_size, void* d_ws, size_t ws_size,
                              hipStream_t stream) {
  const float* x     = (const float*)d_in[0];
  const float* W_dtw = (const float*)d_in[1];
  const float* W_dt  = (const float*)d_in[2];
  const float* b_dt  = (const float*)d_in[3];
  const float* A_log = (const float*)d_in[4];
  const float* W_B   = (const float*)d_in[5];
  const float* W_C   = (const float*)d_in[6];
  const float* Dp    = (const float*)d_in[7];
  const float* ln_g  = (const float*)d_in[8];
  const float* ln_b  = (const float*)d_in[9];
  const float* W_out = (const float*)d_in[10];
  float* out = (float*)d_out;

  float* ws = (float*)d_ws;                        // 59.24 MB total (same as R1/R2)
  float* delta  = ws;                              // 4194304
  float* ypre   = delta + (size_t)BS_ * D_;        // 4194304
  float* Bm     = ypre + (size_t)BS_ * D_;         // 65536
  float* Cm     = Bm + (size_t)BS_ * N_;           // 65536
  float* aprod  = Cm + (size_t)BS_ * N_;           // 2097152
  float* hend   = aprod + (size_t)B_ * NC * D_ * N_;   // 2097152
  float* hstart = hend + (size_t)B_ * NC * D_ * N_;    // 2097152
  // lifetime-disjoint overlays:
  unsigned short* xb   = (unsigned short*)aprod;   // dead before scan1 writes aprod
  float*          part = hend;                     // dead before scan1 writes hend
  unsigned short* dtb  = (unsigned short*)hstart;  // dead before scan2 writes hstart
  unsigned short* wdtb = dtb + (size_t)BS_ * R_;
  unsigned short* Wcat = wdtb + (size_t)D_ * R_;
  unsigned short* ybf  = (unsigned short*)aprod;   // after scan2
  unsigned short* wob  = (unsigned short*)hend;    // after scan2

  k_cast<<<dim3(4096), dim3(256), 0, stream>>>(x, xb, BS_ * D_);
  k_cast<<<dim3(64),   dim3(256), 0, stream>>>(W_dtw, Wcat, R_ * D_);
  k_cast<<<dim3(16),   dim3(256), 0, stream>>>(W_B, Wcat + (size_t)R_ * D_, N_ * D_);
  k_cast<<<dim3(16),   dim3(256), 0, stream>>>(W_C, Wcat + (size_t)(R_ + N_) * D_, N_ * D_);
  k_cast<<<dim3(64),   dim3(256), 0, stream>>>(W_dt, wdtb, D_ * R_);

  k_proj<<<dim3(BS_ / 64, 4), dim3(256), 0, stream>>>(xb, Wcat, part);
  k_projred<<<dim3(BS_ * 96 / 256), dim3(256), 0, stream>>>(part, dtb, Bm, Cm);
  k_delta<<<dim3(BS_ / 128, D_ / 128), dim3(256), 0, stream>>>(dtb, wdtb, b_dt, delta);

  k_scan1<<<dim3(B_ * NC * D_ * 4 / 256), dim3(256), 0, stream>>>(x, delta, Bm, A_log,
                                                                  aprod, hend);
  k_scan2<<<dim3(B_ * D_ * N_ / 256), dim3(256), 0, stream>>>(aprod, hend, hstart);
  k_cast<<<dim3(1024), dim3(256), 0, stream>>>(W_out, wob, D_ * D_);
  k_scan3<<<dim3(B_ * NC * D_ * 4 / 256), dim3(256), 0, stream>>>(x, delta, Bm, Cm,
                                                                  A_log, hstart, Dp, ypre);
  k_ln<<<dim3(BS_), dim3(256), 0, stream>>>(ypre, ln_g, ln_b, ybf);
  k_out<<<dim3(BS_ / 128, D_ / 128), dim3(256), 0, stream>>>(ybf, wob, out);
}

// Round 4
// 114.948 us; speedup vs baseline: 2.8432x; 1.1275x over previous
//
#include <hip/hip_runtime.h>
#include <hip/hip_bf16.h>

#define B_ 2
#define S_ 2048
#define D_ 1024
#define N_ 16
#define R_ 64
#define NC 64          // number of scan chunks
#define CL 32          // chunk length  (NC*CL == S_)
#define BS_ (B_*S_)
#define KSPLIT 8

typedef __attribute__((ext_vector_type(4))) float f32x4;
typedef __attribute__((ext_vector_type(8))) short bf16x8;
typedef __attribute__((ext_vector_type(8))) unsigned short u16x8;

__device__ __forceinline__ unsigned short f2b(float v) {
  unsigned u = __builtin_bit_cast(unsigned, v);
  unsigned r = ((u >> 16) & 1u) + 0x7FFFu;
  return (unsigned short)((u + r) >> 16);
}

__device__ __forceinline__ void gload_lds16(const void* g, void* l) {
  __builtin_amdgcn_global_load_lds(
      (const __attribute__((address_space(1))) unsigned int*)g,
      (__attribute__((address_space(3))) unsigned int*)l, 16, 0, 0);
}

// ---------------- one fused fp32 -> bf16 cast for ALL tensors ----------------
// regions (element offsets), all multiples of 1024 so branches are block-uniform:
//  [0,        4194304) x     -> xb
//  [4194304,  4259840) W_dtw -> Wcat rows 0..63
//  [4259840,  4276224) W_B   -> Wcat rows 64..79
//  [4276224,  4292608) W_C   -> Wcat rows 80..95
//  [4292608,  4358144) W_dt  -> wdtb
//  [4358144,  5406720) W_out -> wob
__global__ __launch_bounds__(256) void k_castall(
    const float* __restrict__ x, const float* __restrict__ W_dtw,
    const float* __restrict__ W_B, const float* __restrict__ W_C,
    const float* __restrict__ W_dt, const float* __restrict__ W_out,
    unsigned short* __restrict__ xb, unsigned short* __restrict__ Wcat,
    unsigned short* __restrict__ wdtb, unsigned short* __restrict__ wob) {
  int i = (blockIdx.x * 256 + threadIdx.x) * 4;   // grid covers 5406720 elems
  const float* s; unsigned short* d; int off;
  if (i < 4194304)      { s = x;     d = xb;           off = 0; }
  else if (i < 4259840) { s = W_dtw; d = Wcat;         off = 4194304; }
  else if (i < 4276224) { s = W_B;   d = Wcat + 65536; off = 4259840; }
  else if (i < 4292608) { s = W_C;   d = Wcat + 81920; off = 4276224; }
  else if (i < 4358144) { s = W_dt;  d = wdtb;         off = 4292608; }
  else                  { s = W_out; d = wob;          off = 4358144; }
  int j = i - off;
  float4 v = *(const float4*)&s[j];
  ushort4 o;
  o.x = f2b(v.x); o.y = f2b(v.y); o.z = f2b(v.z); o.w = f2b(v.w);
  *(ushort4*)&d[j] = o;
}

// ---------------- fused x-projection GEMM, K-split by 8 ----------------
// [4096,1024] x [1024,96] -> fp32 partials part[ksplit][4096][96]
__global__ __launch_bounds__(256, 2) void k_proj(
    const unsigned short* __restrict__ xb, const unsigned short* __restrict__ Wcat,
    float* __restrict__ part) {
  __shared__ __align__(16) unsigned short Xs[2][64 * 64];   // 2x8KB
  __shared__ __align__(16) unsigned short Ws[2][96 * 64];   // 2x12KB
  const int tid = threadIdx.x;
  const int lane = tid & 63, w = tid >> 6;
  const size_t row0 = (size_t)blockIdx.x * 64;
  const int kbase = blockIdx.y * (D_ / KSPLIT);             // 128-wide K slice
  f32x4 acc[6] = {};

  auto stage = [&](int buf, int k0) {
    #pragma unroll
    for (int i = 0; i < 2; ++i) {
      int id = i * 256 + tid; int row = id >> 3, s = id & 7;
      gload_lds16(xb + (row0 + row) * D_ + k0 + ((s ^ (row & 7)) << 3),
                  Xs[buf] + row * 64 + s * 8);
    }
    #pragma unroll
    for (int i = 0; i < 3; ++i) {
      int id = i * 256 + tid; int row = id >> 3, s = id & 7;
      gload_lds16(Wcat + (size_t)row * D_ + k0 + ((s ^ (row & 7)) << 3),
                  Ws[buf] + row * 64 + s * 8);
    }
  };
  stage(0, kbase);
  __syncthreads();
  int cur = 0;
  const int r = lane & 15, kg = lane >> 4;
  for (int t = 0; t < 2; ++t) {
    if (t < 1) stage(cur ^ 1, kbase + 64);
    #pragma unroll
    for (int ks = 0; ks < 2; ++ks) {
      const int arow = w * 16 + r;
      bf16x8 a = *(const bf16x8*)&Xs[cur][arow * 64 + ((((ks << 2) | kg) ^ (arow & 7)) << 3)];
      #pragma unroll
      for (int nt = 0; nt < 6; ++nt) {
        const int brow = nt * 16 + r;
        bf16x8 b = *(const bf16x8*)&Ws[cur][brow * 64 + ((((ks << 2) | kg) ^ (brow & 7)) << 3)];
        acc[nt] = __builtin_amdgcn_mfma_f32_16x16x32_bf16(a, b, acc[nt], 0, 0, 0);
      }
    }
    __syncthreads();
    cur ^= 1;
  }
  const int cr = lane >> 4, cc = lane & 15;
  float* pb = part + (size_t)blockIdx.y * (BS_ * 96);
  #pragma unroll
  for (int nt = 0; nt < 6; ++nt)
    #pragma unroll
    for (int j = 0; j < 4; ++j)
      pb[(row0 + w * 16 + cr * 4 + j) * 96 + nt * 16 + cc] = acc[nt][j];
}

// reduce 8 K-split partials -> dtb (bf16), Bm, Cm (fp32)
__global__ __launch_bounds__(256) void k_projred(
    const float* __restrict__ part, unsigned short* __restrict__ dtb,
    float* __restrict__ Bm, float* __restrict__ Cm) {
  int e = blockIdx.x * 256 + threadIdx.x;        // < 4096*96
  int row = e / 96, col = e - row * 96;
  float s = 0.f;
  #pragma unroll
  for (int p = 0; p < KSPLIT; ++p) s += part[e + (size_t)p * (BS_ * 96)];
  if (col < 64)      dtb[row * R_ + col] = f2b(s);
  else if (col < 80) Bm[row * N_ + col - 64] = s;
  else               Cm[row * N_ + col - 80] = s;
}

// ---------------- delta GEMM: softplus(dt[4096,64] x W_dt^T[64,1024] + b) ----------------
__global__ __launch_bounds__(256) void k_delta(
    const unsigned short* __restrict__ dtb, const unsigned short* __restrict__ wdtb,
    const float* __restrict__ b_dt, float* __restrict__ delta) {
  __shared__ __align__(16) unsigned short As[128 * 64];  // 16KB
  __shared__ __align__(16) unsigned short Bs[128 * 64];  // 16KB
  const int tid = threadIdx.x;
  const int lane = tid & 63, wid = tid >> 6;
  const int wr = wid >> 1, wc = wid & 1;
  const size_t row0 = (size_t)blockIdx.x * 128;
  const size_t col0 = (size_t)blockIdx.y * 128;
  f32x4 acc[4][4] = {};

  {
    const int r = tid >> 3, s = tid & 7;
    #pragma unroll
    for (int i = 0; i < 4; ++i) {
      const int row = i * 32 + r;
      const int gs = s ^ (row & 7);
      gload_lds16(dtb + (row0 + row) * R_ + gs * 8, As + row * 64 + s * 8);
      gload_lds16(wdtb + (col0 + row) * R_ + gs * 8, Bs + row * 64 + s * 8);
    }
  }
  __syncthreads();
  const int r = lane & 15, kg = lane >> 4;
  #pragma unroll
  for (int ks = 0; ks < 2; ++ks) {
    bf16x8 a[4], b[4];
    #pragma unroll
    for (int m = 0; m < 4; ++m) {
      const int arow = wr * 64 + m * 16 + r;
      a[m] = *(const bf16x8*)&As[arow * 64 + (((ks << 2) | kg) ^ (arow & 7)) * 8];
    }
    #pragma unroll
    for (int n = 0; n < 4; ++n) {
      const int brow = wc * 64 + n * 16 + r;
      b[n] = *(const bf16x8*)&Bs[brow * 64 + (((ks << 2) | kg) ^ (brow & 7)) * 8];
    }
    #pragma unroll
    for (int m = 0; m < 4; ++m)
      #pragma unroll
      for (int n = 0; n < 4; ++n)
        acc[m][n] = __builtin_amdgcn_mfma_f32_16x16x32_bf16(a[m], b[n], acc[m][n], 0, 0, 0);
  }
  const int cr = lane >> 4, cc = lane & 15;
  #pragma unroll
  for (int m = 0; m < 4; ++m) {
    #pragma unroll
    for (int n = 0; n < 4; ++n) {
      const int d = (int)col0 + wc * 64 + n * 16 + cc;
      const float bd = b_dt[d];
      #pragma unroll
      for (int j = 0; j < 4; ++j) {
        size_t trow = row0 + wr * 64 + m * 16 + cr * 4 + j;
        float v = acc[m][n][j] + bd;
        float sp = fmaxf(v, 0.f) + log1pf(__expf(-fabsf(v)));
        delta[trow * D_ + d] = sp;
      }
    }
  }
}

// ---------------- scan phase 1: per-chunk summaries, 4 lanes per d ----------------
__global__ __launch_bounds__(256) void k_scan1(
    const float* __restrict__ x, const float* __restrict__ delta,
    const float* __restrict__ Bm, const float* __restrict__ A_log,
    float* __restrict__ aprod, float* __restrict__ hend) {
  int g = blockIdx.x * 256 + threadIdx.x;     // B*NC*D*4 = 524288 threads
  int nq = g & 3;
  int d = (g >> 2) & (D_ - 1);
  int c = (g >> 12) & (NC - 1);
  int b = g >> 18;

  float4 av = *(const float4*)&A_log[(size_t)d * N_ + nq * 4];
  float Ad[4] = {-__expf(av.x), -__expf(av.y), -__expf(av.z), -__expf(av.w)};
  float ap[4] = {1.f, 1.f, 1.f, 1.f}, h[4] = {0.f, 0.f, 0.f, 0.f};

  size_t base = (size_t)(b * S_ + c * CL) * D_ + d;
  size_t bcb  = (size_t)(b * S_ + c * CL) * N_ + nq * 4;
  for (int s = 0; s < CL; ++s) {
    float dlt = delta[base + (size_t)s * D_];
    float xv  = x[base + (size_t)s * D_];
    float dbx = dlt * xv;
    float4 Bv = *(const float4*)&Bm[bcb + (size_t)s * N_];
    float da0 = __expf(dlt * Ad[0]), da1 = __expf(dlt * Ad[1]);
    float da2 = __expf(dlt * Ad[2]), da3 = __expf(dlt * Ad[3]);
    ap[0] *= da0; ap[1] *= da1; ap[2] *= da2; ap[3] *= da3;
    h[0] = da0 * h[0] + dbx * Bv.x;
    h[1] = da1 * h[1] + dbx * Bv.y;
    h[2] = da2 * h[2] + dbx * Bv.z;
    h[3] = da3 * h[3] + dbx * Bv.w;
  }
  size_t o = (((size_t)(b * NC + c)) * D_ + d) * N_ + nq * 4;
  *(float4*)&aprod[o] = make_float4(ap[0], ap[1], ap[2], ap[3]);
  *(float4*)&hend[o]  = make_float4(h[0], h[1], h[2], h[3]);
}

// ---------------- scan phase 2: scan chunk summaries ----------------
__global__ __launch_bounds__(256) void k_scan2(
    const float* __restrict__ aprod, const float* __restrict__ hend,
    float* __restrict__ hstart) {
  int g = blockIdx.x * 256 + threadIdx.x;   // B_*D_*N_ = 32768 threads
  int n = g & (N_ - 1);
  int d = (g >> 4) & (D_ - 1);
  int b = g >> 14;
  float h = 0.f;
  for (int c = 0; c < NC; ++c) {
    size_t idx = (((size_t)b * NC + c) * D_ + d) * N_ + n;
    hstart[idx] = h;
    h = aprod[idx] * h + hend[idx];
  }
}

// ---------------- scan phase 3: recompute + y + fused residual ----------------
__global__ __launch_bounds__(256) void k_scan3(
    const float* __restrict__ x, const float* __restrict__ delta,
    const float* __restrict__ Bm, const float* __restrict__ Cm,
    const float* __restrict__ A_log, const float* __restrict__ hstart,
    const float* __restrict__ Dp, float* __restrict__ ypre) {
  int g = blockIdx.x * 256 + threadIdx.x;
  int nq = g & 3;
  int d = (g >> 2) & (D_ - 1);
  int c = (g >> 12) & (NC - 1);
  int b = g >> 18;

  float4 av = *(const float4*)&A_log[(size_t)d * N_ + nq * 4];
  float Ad[4] = {-__expf(av.x), -__expf(av.y), -__expf(av.z), -__expf(av.w)};
  float h[4];
  {
    size_t o = (((size_t)(b * NC + c)) * D_ + d) * N_ + nq * 4;
    float4 v = *(const float4*)&hstart[o];
    h[0] = v.x; h[1] = v.y; h[2] = v.z; h[3] = v.w;
  }
  const float Dpd = Dp[d];

  size_t base = (size_t)(b * S_ + c * CL) * D_ + d;
  size_t bcb  = (size_t)(b * S_ + c * CL) * N_ + nq * 4;
  for (int s = 0; s < CL; ++s) {
    float dlt = delta[base + (size_t)s * D_];
    float xv  = x[base + (size_t)s * D_];
    float dbx = dlt * xv;
    float4 Bv = *(const float4*)&Bm[bcb + (size_t)s * N_];
    float4 Cv = *(const float4*)&Cm[bcb + (size_t)s * N_];
    float da0 = __expf(dlt * Ad[0]), da1 = __expf(dlt * Ad[1]);
    float da2 = __expf(dlt * Ad[2]), da3 = __expf(dlt * Ad[3]);
    h[0] = da0 * h[0] + dbx * Bv.x;
    h[1] = da1 * h[1] + dbx * Bv.y;
    h[2] = da2 * h[2] + dbx * Bv.z;
    h[3] = da3 * h[3] + dbx * Bv.w;
    float y = h[0] * Cv.x + h[1] * Cv.y + h[2] * Cv.z + h[3] * Cv.w;
    y += __shfl_xor(y, 1);
    y += __shfl_xor(y, 2);
    if (nq == 0) ypre[base + (size_t)s * D_] = y + Dpd * xv;
  }
}

// ---------------- layernorm (residual already fused) -> bf16 y ----------------
__device__ __forceinline__ float block_sum256(float v, float* sm) {
  #pragma unroll
  for (int o = 32; o > 0; o >>= 1) v += __shfl_down(v, o, 64);
  int w = threadIdx.x >> 6;
  __syncthreads();
  if ((threadIdx.x & 63) == 0) sm[w] = v;
  __syncthreads();
  return (sm[0] + sm[1]) + (sm[2] + sm[3]);
}

__global__ __launch_bounds__(256) void k_ln(
    const float* __restrict__ ypre, const float* __restrict__ g,
    const float* __restrict__ bta, unsigned short* __restrict__ ybf) {
  __shared__ float sm[4];
  const int t = blockIdx.x;
  const int tid = threadIdx.x;
  size_t base = (size_t)t * D_ + tid * 4;
  float4 v = *(const float4*)&ypre[base];
  float s1 = block_sum256(v.x + v.y + v.z + v.w, sm);
  float mu = s1 * (1.f / D_);
  float cx = v.x - mu, cy = v.y - mu, cz = v.z - mu, cw = v.w - mu;
  float s2 = block_sum256(cx*cx + cy*cy + cz*cz + cw*cw, sm);
  float rs = rsqrtf(s2 * (1.f / D_) + 1e-5f);
  float4 gg = *(const float4*)&g[tid * 4];
  float4 bb = *(const float4*)&bta[tid * 4];
  ushort4 o;
  o.x = f2b(cx * rs * gg.x + bb.x);
  o.y = f2b(cy * rs * gg.y + bb.y);
  o.z = f2b(cz * rs * gg.z + bb.z);
  o.w = f2b(cw * rs * gg.w + bb.w);
  *(ushort4*)&ybf[base] = o;
}

// ---------------- output GEMM: O = Y[4096,1024] x W_out^T, bf16 MFMA ----------------
// BM=128, BN=64 -> grid (32,16)=512 blocks, 48KB LDS -> 2 blocks/CU co-resident
__device__ __forceinline__ void stage128x64(const unsigned short* __restrict__ g,
                                            size_t row0, int k0,
                                            unsigned short* lds, int tid) {
  const int r = tid >> 3, s = tid & 7;
  #pragma unroll
  for (int i = 0; i < 4; ++i) {
    const int row = i * 32 + r;
    const int gs = s ^ (row & 7);
    gload_lds16(g + ((row0 + row) << 10) + k0 + (gs << 3), lds + row * 64 + s * 8);
  }
}

__device__ __forceinline__ void stage64x64(const unsigned short* __restrict__ g,
                                           size_t row0, int k0,
                                           unsigned short* lds, int tid) {
  const int r = tid >> 3, s = tid & 7;   // r in 0..31
  #pragma unroll
  for (int i = 0; i < 2; ++i) {
    const int row = i * 32 + r;
    const int gs = s ^ (row & 7);
    gload_lds16(g + ((row0 + row) << 10) + k0 + (gs << 3), lds + row * 64 + s * 8);
  }
}

__global__ __launch_bounds__(256, 2) void k_out(const unsigned short* __restrict__ Y,
                                                const unsigned short* __restrict__ W,
                                                float* __restrict__ O) {
  __shared__ __align__(16) unsigned short As[2][128 * 64];  // 2x16KB
  __shared__ __align__(16) unsigned short Bs[2][64 * 64];   // 2x8KB
  const int tid = threadIdx.x;
  const int lane = tid & 63, wid = tid >> 6;
  const size_t row0 = (size_t)blockIdx.x * 128;
  const size_t col0 = (size_t)blockIdx.y * 64;
  f32x4 acc[2][4] = {};

  stage128x64(Y, row0, 0, As[0], tid);
  stage64x64(W, col0, 0, Bs[0], tid);
  __syncthreads();

  int cur = 0;
  const int r = lane & 15, kg = lane >> 4;
  for (int t = 0; t < 16; ++t) {
    if (t + 1 < 16) {
      stage128x64(Y, row0, (t + 1) * 64, As[cur ^ 1], tid);
      stage64x64(W, col0, (t + 1) * 64, Bs[cur ^ 1], tid);
    }
    #pragma unroll
    for (int ks = 0; ks < 2; ++ks) {
      bf16x8 a[2], b[4];
      #pragma unroll
      for (int m = 0; m < 2; ++m) {
        const int arow = wid * 32 + m * 16 + r;
        a[m] = *(const bf16x8*)&As[cur][arow * 64 + (((ks << 2) | kg) ^ (arow & 7)) * 8];
      }
      #pragma unroll
      for (int n = 0; n < 4; ++n) {
        const int brow = n * 16 + r;
        b[n] = *(const bf16x8*)&Bs[cur][brow * 64 + (((ks << 2) | kg) ^ (brow & 7)) * 8];
      }
      #pragma unroll
      for (int m = 0; m < 2; ++m)
        #pragma unroll
        for (int n = 0; n < 4; ++n)
          acc[m][n] = __builtin_amdgcn_mfma_f32_16x16x32_bf16(a[m], b[n], acc[m][n], 0, 0, 0);
    }
    __syncthreads();
    cur ^= 1;
  }

  const int cr = lane >> 4, cc = lane & 15;
  #pragma unroll
  for (int m = 0; m < 2; ++m) {
    #pragma unroll
    for (int n = 0; n < 4; ++n) {
      size_t orow = row0 + wid * 32 + m * 16 + cr * 4;
      float* op = O + orow * D_ + col0 + n * 16 + cc;
      #pragma unroll
      for (int j = 0; j < 4; ++j) op[(size_t)j * D_] = acc[m][n][j];
    }
  }
}

extern "C" void kernel_launch(void* const* d_in, const int* in_sizes, int n_in,
                              void* d_out, int out_size, void* d_ws, size_t ws_size,
                              hipStream_t stream) {
  const float* x     = (const float*)d_in[0];
  const float* W_dtw = (const float*)d_in[1];
  const float* W_dt  = (const float*)d_in[2];
  const float* b_dt  = (const float*)d_in[3];
  const float* A_log = (const float*)d_in[4];
  const float* W_B   = (const float*)d_in[5];
  const float* W_C   = (const float*)d_in[6];
  const float* Dp    = (const float*)d_in[7];
  const float* ln_g  = (const float*)d_in[8];
  const float* ln_b  = (const float*)d_in[9];
  const float* W_out = (const float*)d_in[10];
  float* out = (float*)d_out;

  // ws_size = 256 MiB (confirmed via harness fill dispatches); ~92 MB used,
  // every buffer dedicated -- no lifetime overlays.
  float* ws = (float*)d_ws;
  float* delta  = ws;                                   // 4,194,304 f
  float* ypre   = delta  + (size_t)BS_ * D_;            // 4,194,304 f
  float* Bm     = ypre   + (size_t)BS_ * D_;            //    65,536 f
  float* Cm     = Bm     + (size_t)BS_ * N_;            //    65,536 f
  float* aprod  = Cm     + (size_t)BS_ * N_;            // 2,097,152 f
  float* hend   = aprod  + (size_t)B_ * NC * D_ * N_;   // 2,097,152 f
  float* hstart = hend   + (size_t)B_ * NC * D_ * N_;   // 2,097,152 f
  float* part   = hstart + (size_t)B_ * NC * D_ * N_;   // 3,145,728 f (8*4096*96)
  unsigned short* xb   = (unsigned short*)(part + (size_t)KSPLIT * BS_ * 96);
  unsigned short* Wcat = xb   + (size_t)BS_ * D_;       // 98,304 u16
  unsigned short* wdtb = Wcat + (size_t)96 * D_;        // 65,536 u16
  unsigned short* wob  = wdtb + (size_t)D_ * R_;        // 1,048,576 u16
  unsigned short* ybf  = wob  + (size_t)D_ * D_;        // 4,194,304 u16
  unsigned short* dtb  = ybf  + (size_t)BS_ * D_;       // 262,144 u16

  k_castall<<<dim3(5280), dim3(256), 0, stream>>>(x, W_dtw, W_B, W_C, W_dt, W_out,
                                                  xb, Wcat, wdtb, wob);
  k_proj<<<dim3(BS_ / 64, KSPLIT), dim3(256), 0, stream>>>(xb, Wcat, part);
  k_projred<<<dim3(BS_ * 96 / 256), dim3(256), 0, stream>>>(part, dtb, Bm, Cm);
  k_delta<<<dim3(BS_ / 128, D_ / 128), dim3(256), 0, stream>>>(dtb, wdtb, b_dt, delta);
  k_scan1<<<dim3(B_ * NC * D_ * 4 / 256), dim3(256), 0, stream>>>(x, delta, Bm, A_log,
                                                                  aprod, hend);
  k_scan2<<<dim3(B_ * D_ * N_ / 256), dim3(256), 0, stream>>>(aprod, hend, hstart);
  k_scan3<<<dim3(B_ * NC * D_ * 4 / 256), dim3(256), 0, stream>>>(x, delta, Bm, Cm,
                                                                  A_log, hstart, Dp, ypre);
  k_ln<<<dim3(BS_), dim3(256), 0, stream>>>(ypre, ln_g, ln_b, ybf);
  k_out<<<dim3(BS_ / 128, D_ / 64), dim3(256), 0, stream>>>(ybf, wob, out);
}

// Round 5
// 110.624 us; speedup vs baseline: 2.9543x; 1.0391x over previous
//
#include <hip/hip_runtime.h>
#include <hip/hip_bf16.h>

#define B_ 2
#define S_ 2048
#define D_ 1024
#define N_ 16
#define R_ 64
#define NC 64          // number of scan chunks
#define CL 32          // chunk length  (NC*CL == S_)
#define BS_ (B_*S_)
#define KSPLIT 8

typedef __attribute__((ext_vector_type(4))) float f32x4;
typedef __attribute__((ext_vector_type(8))) short bf16x8;
typedef __attribute__((ext_vector_type(8))) unsigned short u16x8;

__device__ __forceinline__ unsigned short f2b(float v) {
  unsigned u = __builtin_bit_cast(unsigned, v);
  unsigned r = ((u >> 16) & 1u) + 0x7FFFu;
  return (unsigned short)((u + r) >> 16);
}

__device__ __forceinline__ void gload_lds16(const void* g, void* l) {
  __builtin_amdgcn_global_load_lds(
      (const __attribute__((address_space(1))) unsigned int*)g,
      (__attribute__((address_space(3))) unsigned int*)l, 16, 0, 0);
}

// ---------------- fp32 -> bf16 cast for WEIGHTS only (x is cast inline in k_proj) ----
// regions (element offsets, all multiples of 1024):
//  [0,      65536)  W_dtw -> Wcat rows 0..63
//  [65536,  81920)  W_B   -> Wcat rows 64..79
//  [81920,  98304)  W_C   -> Wcat rows 80..95
//  [98304, 163840)  W_dt  -> wdtb
//  [163840,1212416) W_out -> wob
__global__ __launch_bounds__(256) void k_castall(
    const float* __restrict__ W_dtw, const float* __restrict__ W_B,
    const float* __restrict__ W_C, const float* __restrict__ W_dt,
    const float* __restrict__ W_out,
    unsigned short* __restrict__ Wcat, unsigned short* __restrict__ wdtb,
    unsigned short* __restrict__ wob) {
  int i = (blockIdx.x * 256 + threadIdx.x) * 4;   // grid covers 1212416 elems
  const float* s; unsigned short* d; int off;
  if (i < 65536)       { s = W_dtw; d = Wcat;         off = 0; }
  else if (i < 81920)  { s = W_B;   d = Wcat + 65536; off = 65536; }
  else if (i < 98304)  { s = W_C;   d = Wcat + 81920; off = 81920; }
  else if (i < 163840) { s = W_dt;  d = wdtb;         off = 98304; }
  else                 { s = W_out; d = wob;          off = 163840; }
  int j = i - off;
  float4 v = *(const float4*)&s[j];
  ushort4 o;
  o.x = f2b(v.x); o.y = f2b(v.y); o.z = f2b(v.z); o.w = f2b(v.w);
  *(ushort4*)&d[j] = o;
}

// ---------------- fused x-projection GEMM, K-split by 8, inline x cast ----------------
// [4096,1024] x [1024,96] -> fp32 partials part[ksplit][4096][96]
__global__ __launch_bounds__(256, 2) void k_proj(
    const float* __restrict__ x, const unsigned short* __restrict__ Wcat,
    float* __restrict__ part) {
  __shared__ __align__(16) unsigned short Xs[2][64 * 64];   // 2x8KB
  __shared__ __align__(16) unsigned short Ws[2][96 * 64];   // 2x12KB
  const int tid = threadIdx.x;
  const int lane = tid & 63, w = tid >> 6;
  const size_t row0 = (size_t)blockIdx.x * 64;
  const int kbase = blockIdx.y * (D_ / KSPLIT);             // 128-wide K slice
  f32x4 acc[6] = {};

  auto stage = [&](int buf, int k0) {
    // x tile 64x64: reg-stage fp32 -> bf16, swizzled ds_write
    #pragma unroll
    for (int i = 0; i < 2; ++i) {
      int id = i * 256 + tid; int row = id >> 3, s = id & 7;
      const float* gp = &x[(row0 + row) * D_ + k0 + s * 8];
      float4 v0 = *(const float4*)gp;
      float4 v1 = *(const float4*)(gp + 4);
      u16x8 u;
      u[0] = f2b(v0.x); u[1] = f2b(v0.y); u[2] = f2b(v0.z); u[3] = f2b(v0.w);
      u[4] = f2b(v1.x); u[5] = f2b(v1.y); u[6] = f2b(v1.z); u[7] = f2b(v1.w);
      *(u16x8*)&Xs[buf][row * 64 + ((s ^ (row & 7)) << 3)] = u;
    }
    // W tile 96x64: async, pre-swizzled source + linear LDS dest
    #pragma unroll
    for (int i = 0; i < 3; ++i) {
      int id = i * 256 + tid; int row = id >> 3, s = id & 7;
      gload_lds16(Wcat + (size_t)row * D_ + k0 + ((s ^ (row & 7)) << 3),
                  Ws[buf] + row * 64 + s * 8);
    }
  };
  stage(0, kbase);
  __syncthreads();
  int cur = 0;
  const int r = lane & 15, kg = lane >> 4;
  for (int t = 0; t < 2; ++t) {
    if (t < 1) stage(cur ^ 1, kbase + 64);
    #pragma unroll
    for (int ks = 0; ks < 2; ++ks) {
      const int arow = w * 16 + r;
      bf16x8 a = *(const bf16x8*)&Xs[cur][arow * 64 + ((((ks << 2) | kg) ^ (arow & 7)) << 3)];
      #pragma unroll
      for (int nt = 0; nt < 6; ++nt) {
        const int brow = nt * 16 + r;
        bf16x8 b = *(const bf16x8*)&Ws[cur][brow * 64 + ((((ks << 2) | kg) ^ (brow & 7)) << 3)];
        acc[nt] = __builtin_amdgcn_mfma_f32_16x16x32_bf16(a, b, acc[nt], 0, 0, 0);
      }
    }
    __syncthreads();
    cur ^= 1;
  }
  const int cr = lane >> 4, cc = lane & 15;
  float* pb = part + (size_t)blockIdx.y * (BS_ * 96);
  #pragma unroll
  for (int nt = 0; nt < 6; ++nt)
    #pragma unroll
    for (int j = 0; j < 4; ++j)
      pb[(row0 + w * 16 + cr * 4 + j) * 96 + nt * 16 + cc] = acc[nt][j];
}

// reduce 8 K-split partials -> dtb (bf16), Bm, Cm (fp32)
__global__ __launch_bounds__(256) void k_projred(
    const float* __restrict__ part, unsigned short* __restrict__ dtb,
    float* __restrict__ Bm, float* __restrict__ Cm) {
  int e = blockIdx.x * 256 + threadIdx.x;        // < 4096*96
  int row = e / 96, col = e - row * 96;
  float s = 0.f;
  #pragma unroll
  for (int p = 0; p < KSPLIT; ++p) s += part[e + (size_t)p * (BS_ * 96)];
  if (col < 64)      dtb[row * R_ + col] = f2b(s);
  else if (col < 80) Bm[row * N_ + col - 64] = s;
  else               Cm[row * N_ + col - 80] = s;
}

// ---------------- delta GEMM: softplus(dt[4096,64] x W_dt^T[64,1024] + b) ----------------
__global__ __launch_bounds__(256) void k_delta(
    const unsigned short* __restrict__ dtb, const unsigned short* __restrict__ wdtb,
    const float* __restrict__ b_dt, float* __restrict__ delta) {
  __shared__ __align__(16) unsigned short As[128 * 64];  // 16KB
  __shared__ __align__(16) unsigned short Bs[128 * 64];  // 16KB
  const int tid = threadIdx.x;
  const int lane = tid & 63, wid = tid >> 6;
  const int wr = wid >> 1, wc = wid & 1;
  const size_t row0 = (size_t)blockIdx.x * 128;
  const size_t col0 = (size_t)blockIdx.y * 128;
  f32x4 acc[4][4] = {};

  {
    const int r = tid >> 3, s = tid & 7;
    #pragma unroll
    for (int i = 0; i < 4; ++i) {
      const int row = i * 32 + r;
      const int gs = s ^ (row & 7);
      gload_lds16(dtb + (row0 + row) * R_ + gs * 8, As + row * 64 + s * 8);
      gload_lds16(wdtb + (col0 + row) * R_ + gs * 8, Bs + row * 64 + s * 8);
    }
  }
  __syncthreads();
  const int r = lane & 15, kg = lane >> 4;
  #pragma unroll
  for (int ks = 0; ks < 2; ++ks) {
    bf16x8 a[4], b[4];
    #pragma unroll
    for (int m = 0; m < 4; ++m) {
      const int arow = wr * 64 + m * 16 + r;
      a[m] = *(const bf16x8*)&As[arow * 64 + (((ks << 2) | kg) ^ (arow & 7)) * 8];
    }
    #pragma unroll
    for (int n = 0; n < 4; ++n) {
      const int brow = wc * 64 + n * 16 + r;
      b[n] = *(const bf16x8*)&Bs[brow * 64 + (((ks << 2) | kg) ^ (brow & 7)) * 8];
    }
    #pragma unroll
    for (int m = 0; m < 4; ++m)
      #pragma unroll
      for (int n = 0; n < 4; ++n)
        acc[m][n] = __builtin_amdgcn_mfma_f32_16x16x32_bf16(a[m], b[n], acc[m][n], 0, 0, 0);
  }
  const int cr = lane >> 4, cc = lane & 15;
  #pragma unroll
  for (int m = 0; m < 4; ++m) {
    #pragma unroll
    for (int n = 0; n < 4; ++n) {
      const int d = (int)col0 + wc * 64 + n * 16 + cc;
      const float bd = b_dt[d];
      #pragma unroll
      for (int j = 0; j < 4; ++j) {
        size_t trow = row0 + wr * 64 + m * 16 + cr * 4 + j;
        float v = acc[m][n][j] + bd;
        float sp = fmaxf(v, 0.f) + log1pf(__expf(-fabsf(v)));
        delta[trow * D_ + d] = sp;
      }
    }
  }
}

// ---------------- scan phase 1: per-chunk summaries, LDS-staged ----------------
// block = one (b, chunk, 64-d slab); thread = (dl, nq): 64 d x 4 n-quads
__global__ __launch_bounds__(256) void k_scan1(
    const float* __restrict__ x, const float* __restrict__ delta,
    const float* __restrict__ Bm, const float* __restrict__ A_log,
    float* __restrict__ aprod, float* __restrict__ hend) {
  __shared__ __align__(16) float sd[CL][64];
  __shared__ __align__(16) float sx[CL][64];
  __shared__ __align__(16) float sB[CL][N_];
  const int tid = threadIdx.x;
  const int db = blockIdx.x & 15;
  const int c  = (blockIdx.x >> 4) & (NC - 1);
  const int b  = blockIdx.x >> 10;
  const int d0 = db * 64;
  const size_t tokbase = (size_t)(b * S_ + c * CL);

  {   // async stage (per-lane lds ptr == base + lane*16 in every call)
    int s = tid >> 4, jf = (tid & 15) * 4;         // 16 rows per call
    size_t g = (tokbase + s) * D_ + d0 + jf;
    gload_lds16(&delta[g], &sd[s][jf]);
    gload_lds16(&x[g],     &sx[s][jf]);
    gload_lds16(&delta[g + (size_t)16 * D_], &sd[s + 16][jf]);
    gload_lds16(&x[g + (size_t)16 * D_],     &sx[s + 16][jf]);
    if (tid < 128) {
      int s2 = tid >> 2, nf = (tid & 3) * 4;
      gload_lds16(&Bm[(tokbase + s2) * N_ + nf], &sB[s2][nf]);
    }
  }
  const int nq = tid & 3, dl = tid >> 2;
  const int d = d0 + dl;
  float4 av = *(const float4*)&A_log[(size_t)d * N_ + nq * 4];
  float Ad0 = -__expf(av.x), Ad1 = -__expf(av.y);
  float Ad2 = -__expf(av.z), Ad3 = -__expf(av.w);
  __syncthreads();

  float ap0 = 1.f, ap1 = 1.f, ap2 = 1.f, ap3 = 1.f;
  float h0 = 0.f, h1 = 0.f, h2 = 0.f, h3 = 0.f;
  #pragma unroll 8
  for (int s = 0; s < CL; ++s) {
    float dlt = sd[s][dl];
    float dbx = dlt * sx[s][dl];
    float4 Bv = *(const float4*)&sB[s][nq * 4];
    float da0 = __expf(dlt * Ad0), da1 = __expf(dlt * Ad1);
    float da2 = __expf(dlt * Ad2), da3 = __expf(dlt * Ad3);
    ap0 *= da0; ap1 *= da1; ap2 *= da2; ap3 *= da3;
    h0 = da0 * h0 + dbx * Bv.x;
    h1 = da1 * h1 + dbx * Bv.y;
    h2 = da2 * h2 + dbx * Bv.z;
    h3 = da3 * h3 + dbx * Bv.w;
  }
  size_t o = (((size_t)(b * NC + c)) * D_ + d) * N_ + nq * 4;
  *(float4*)&aprod[o] = make_float4(ap0, ap1, ap2, ap3);
  *(float4*)&hend[o]  = make_float4(h0, h1, h2, h3);
}

// ---------------- scan phase 2: scan chunk summaries ----------------
__global__ __launch_bounds__(256) void k_scan2(
    const float* __restrict__ aprod, const float* __restrict__ hend,
    float* __restrict__ hstart) {
  int g = blockIdx.x * 256 + threadIdx.x;   // B_*D_*N_ = 32768 threads
  int n = g & (N_ - 1);
  int d = (g >> 4) & (D_ - 1);
  int b = g >> 14;
  float h = 0.f;
  for (int c = 0; c < NC; ++c) {
    size_t idx = (((size_t)b * NC + c) * D_ + d) * N_ + n;
    hstart[idx] = h;
    h = aprod[idx] * h + hend[idx];
  }
}

// ---------------- scan phase 3: recompute + y + fused residual, LDS-staged ----------------
__global__ __launch_bounds__(256) void k_scan3(
    const float* __restrict__ x, const float* __restrict__ delta,
    const float* __restrict__ Bm, const float* __restrict__ Cm,
    const float* __restrict__ A_log, const float* __restrict__ hstart,
    const float* __restrict__ Dp, float* __restrict__ ypre) {
  __shared__ __align__(16) float sd[CL][64];
  __shared__ __align__(16) float sx[CL][64];
  __shared__ __align__(16) float sB[CL][N_];
  __shared__ __align__(16) float sC[CL][N_];
  __shared__ __align__(16) float sy[CL][64];
  const int tid = threadIdx.x;
  const int db = blockIdx.x & 15;
  const int c  = (blockIdx.x >> 4) & (NC - 1);
  const int b  = blockIdx.x >> 10;
  const int d0 = db * 64;
  const size_t tokbase = (size_t)(b * S_ + c * CL);

  {
    int s = tid >> 4, jf = (tid & 15) * 4;
    size_t g = (tokbase + s) * D_ + d0 + jf;
    gload_lds16(&delta[g], &sd[s][jf]);
    gload_lds16(&x[g],     &sx[s][jf]);
    gload_lds16(&delta[g + (size_t)16 * D_], &sd[s + 16][jf]);
    gload_lds16(&x[g + (size_t)16 * D_],     &sx[s + 16][jf]);
    if (tid < 128) {
      int s2 = tid >> 2, nf = (tid & 3) * 4;
      gload_lds16(&Bm[(tokbase + s2) * N_ + nf], &sB[s2][nf]);
      gload_lds16(&Cm[(tokbase + s2) * N_ + nf], &sC[s2][nf]);
    }
  }
  const int nq = tid & 3, dl = tid >> 2;
  const int d = d0 + dl;
  float4 av = *(const float4*)&A_log[(size_t)d * N_ + nq * 4];
  float Ad0 = -__expf(av.x), Ad1 = -__expf(av.y);
  float Ad2 = -__expf(av.z), Ad3 = -__expf(av.w);
  float h0, h1, h2, h3;
  {
    size_t o = (((size_t)(b * NC + c)) * D_ + d) * N_ + nq * 4;
    float4 v = *(const float4*)&hstart[o];
    h0 = v.x; h1 = v.y; h2 = v.z; h3 = v.w;
  }
  const float Dpd = Dp[d];
  __syncthreads();

  #pragma unroll 8
  for (int s = 0; s < CL; ++s) {
    float dlt = sd[s][dl];
    float xv  = sx[s][dl];
    float dbx = dlt * xv;
    float4 Bv = *(const float4*)&sB[s][nq * 4];
    float4 Cv = *(const float4*)&sC[s][nq * 4];
    float da0 = __expf(dlt * Ad0), da1 = __expf(dlt * Ad1);
    float da2 = __expf(dlt * Ad2), da3 = __expf(dlt * Ad3);
    h0 = da0 * h0 + dbx * Bv.x;
    h1 = da1 * h1 + dbx * Bv.y;
    h2 = da2 * h2 + dbx * Bv.z;
    h3 = da3 * h3 + dbx * Bv.w;
    float y = h0 * Cv.x + h1 * Cv.y + h2 * Cv.z + h3 * Cv.w;
    y += __shfl_xor(y, 1);
    y += __shfl_xor(y, 2);
    if (nq == 0) sy[s][dl] = y + Dpd * xv;
  }
  __syncthreads();
  {   // coalesced bulk write of the y tile
    int s = tid >> 3, j = (tid & 7) * 8;
    size_t g = (tokbase + s) * D_ + d0 + j;
    *(float4*)&ypre[g]     = *(float4*)&sy[s][j];
    *(float4*)&ypre[g + 4] = *(float4*)&sy[s][j + 4];
  }
}

// ---------------- layernorm (residual already fused) -> bf16 y ----------------
__device__ __forceinline__ float block_sum256(float v, float* sm) {
  #pragma unroll
  for (int o = 32; o > 0; o >>= 1) v += __shfl_down(v, o, 64);
  int w = threadIdx.x >> 6;
  __syncthreads();
  if ((threadIdx.x & 63) == 0) sm[w] = v;
  __syncthreads();
  return (sm[0] + sm[1]) + (sm[2] + sm[3]);
}

__global__ __launch_bounds__(256) void k_ln(
    const float* __restrict__ ypre, const float* __restrict__ g,
    const float* __restrict__ bta, unsigned short* __restrict__ ybf) {
  __shared__ float sm[4];
  const int t = blockIdx.x;
  const int tid = threadIdx.x;
  size_t base = (size_t)t * D_ + tid * 4;
  float4 v = *(const float4*)&ypre[base];
  float s1 = block_sum256(v.x + v.y + v.z + v.w, sm);
  float mu = s1 * (1.f / D_);
  float cx = v.x - mu, cy = v.y - mu, cz = v.z - mu, cw = v.w - mu;
  float s2 = block_sum256(cx*cx + cy*cy + cz*cz + cw*cw, sm);
  float rs = rsqrtf(s2 * (1.f / D_) + 1e-5f);
  float4 gg = *(const float4*)&g[tid * 4];
  float4 bb = *(const float4*)&bta[tid * 4];
  ushort4 o;
  o.x = f2b(cx * rs * gg.x + bb.x);
  o.y = f2b(cy * rs * gg.y + bb.y);
  o.z = f2b(cz * rs * gg.z + bb.z);
  o.w = f2b(cw * rs * gg.w + bb.w);
  *(ushort4*)&ybf[base] = o;
}

// ---------------- output GEMM: O = Y[4096,1024] x W_out^T, bf16 MFMA ----------------
__device__ __forceinline__ void stage128x64(const unsigned short* __restrict__ g,
                                            size_t row0, int k0,
                                            unsigned short* lds, int tid) {
  const int r = tid >> 3, s = tid & 7;
  #pragma unroll
  for (int i = 0; i < 4; ++i) {
    const int row = i * 32 + r;
    const int gs = s ^ (row & 7);
    gload_lds16(g + ((row0 + row) << 10) + k0 + (gs << 3), lds + row * 64 + s * 8);
  }
}

__device__ __forceinline__ void stage64x64(const unsigned short* __restrict__ g,
                                           size_t row0, int k0,
                                           unsigned short* lds, int tid) {
  const int r = tid >> 3, s = tid & 7;   // r in 0..31
  #pragma unroll
  for (int i = 0; i < 2; ++i) {
    const int row = i * 32 + r;
    const int gs = s ^ (row & 7);
    gload_lds16(g + ((row0 + row) << 10) + k0 + (gs << 3), lds + row * 64 + s * 8);
  }
}

__global__ __launch_bounds__(256, 2) void k_out(const unsigned short* __restrict__ Y,
                                                const unsigned short* __restrict__ W,
                                                float* __restrict__ O) {
  __shared__ __align__(16) unsigned short As[2][128 * 64];  // 2x16KB
  __shared__ __align__(16) unsigned short Bs[2][64 * 64];   // 2x8KB
  const int tid = threadIdx.x;
  const int lane = tid & 63, wid = tid >> 6;
  const size_t row0 = (size_t)blockIdx.x * 128;
  const size_t col0 = (size_t)blockIdx.y * 64;
  f32x4 acc[2][4] = {};

  stage128x64(Y, row0, 0, As[0], tid);
  stage64x64(W, col0, 0, Bs[0], tid);
  __syncthreads();

  int cur = 0;
  const int r = lane & 15, kg = lane >> 4;
  for (int t = 0; t < 16; ++t) {
    if (t + 1 < 16) {
      stage128x64(Y, row0, (t + 1) * 64, As[cur ^ 1], tid);
      stage64x64(W, col0, (t + 1) * 64, Bs[cur ^ 1], tid);
    }
    #pragma unroll
    for (int ks = 0; ks < 2; ++ks) {
      bf16x8 a[2], b[4];
      #pragma unroll
      for (int m = 0; m < 2; ++m) {
        const int arow = wid * 32 + m * 16 + r;
        a[m] = *(const bf16x8*)&As[cur][arow * 64 + (((ks << 2) | kg) ^ (arow & 7)) * 8];
      }
      #pragma unroll
      for (int n = 0; n < 4; ++n) {
        const int brow = n * 16 + r;
        b[n] = *(const bf16x8*)&Bs[cur][brow * 64 + (((ks << 2) | kg) ^ (brow & 7)) * 8];
      }
      #pragma unroll
      for (int m = 0; m < 2; ++m)
        #pragma unroll
        for (int n = 0; n < 4; ++n)
          acc[m][n] = __builtin_amdgcn_mfma_f32_16x16x32_bf16(a[m], b[n], acc[m][n], 0, 0, 0);
    }
    __syncthreads();
    cur ^= 1;
  }

  const int cr = lane >> 4, cc = lane & 15;
  #pragma unroll
  for (int m = 0; m < 2; ++m) {
    #pragma unroll
    for (int n = 0; n < 4; ++n) {
      size_t orow = row0 + wid * 32 + m * 16 + cr * 4;
      float* op = O + orow * D_ + col0 + n * 16 + cc;
      #pragma unroll
      for (int j = 0; j < 4; ++j) op[(size_t)j * D_] = acc[m][n][j];
    }
  }
}

extern "C" void kernel_launch(void* const* d_in, const int* in_sizes, int n_in,
                              void* d_out, int out_size, void* d_ws, size_t ws_size,
                              hipStream_t stream) {
  const float* x     = (const float*)d_in[0];
  const float* W_dtw = (const float*)d_in[1];
  const float* W_dt  = (const float*)d_in[2];
  const float* b_dt  = (const float*)d_in[3];
  const float* A_log = (const float*)d_in[4];
  const float* W_B   = (const float*)d_in[5];
  const float* W_C   = (const float*)d_in[6];
  const float* Dp    = (const float*)d_in[7];
  const float* ln_g  = (const float*)d_in[8];
  const float* ln_b  = (const float*)d_in[9];
  const float* W_out = (const float*)d_in[10];
  float* out = (float*)d_out;

  // ws_size = 256 MiB; ~83 MB used, all buffers dedicated.
  float* ws = (float*)d_ws;
  float* delta  = ws;                                   // 4,194,304 f
  float* ypre   = delta  + (size_t)BS_ * D_;            // 4,194,304 f
  float* Bm     = ypre   + (size_t)BS_ * D_;            //    65,536 f
  float* Cm     = Bm     + (size_t)BS_ * N_;            //    65,536 f
  float* aprod  = Cm     + (size_t)BS_ * N_;            // 2,097,152 f
  float* hend   = aprod  + (size_t)B_ * NC * D_ * N_;   // 2,097,152 f
  float* hstart = hend   + (size_t)B_ * NC * D_ * N_;   // 2,097,152 f
  float* part   = hstart + (size_t)B_ * NC * D_ * N_;   // 3,145,728 f (8*4096*96)
  unsigned short* Wcat = (unsigned short*)(part + (size_t)KSPLIT * BS_ * 96);
  unsigned short* wdtb = Wcat + (size_t)96 * D_;        // 65,536 u16
  unsigned short* wob  = wdtb + (size_t)D_ * R_;        // 1,048,576 u16
  unsigned short* ybf  = wob  + (size_t)D_ * D_;        // 4,194,304 u16
  unsigned short* dtb  = ybf  + (size_t)BS_ * D_;       // 262,144 u16

  k_castall<<<dim3(1184), dim3(256), 0, stream>>>(W_dtw, W_B, W_C, W_dt, W_out,
                                                  Wcat, wdtb, wob);
  k_proj<<<dim3(BS_ / 64, KSPLIT), dim3(256), 0, stream>>>(x, Wcat, part);
  k_projred<<<dim3(BS_ * 96 / 256), dim3(256), 0, stream>>>(part, dtb, Bm, Cm);
  k_delta<<<dim3(BS_ / 128, D_ / 128), dim3(256), 0, stream>>>(dtb, wdtb, b_dt, delta);
  k_scan1<<<dim3(B_ * NC * (D_ / 64)), dim3(256), 0, stream>>>(x, delta, Bm, A_log,
                                                               aprod, hend);
  k_scan2<<<dim3(B_ * D_ * N_ / 256), dim3(256), 0, stream>>>(aprod, hend, hstart);
  k_scan3<<<dim3(B_ * NC * (D_ / 64)), dim3(256), 0, stream>>>(x, delta, Bm, Cm,
                                                               A_log, hstart, Dp, ypre);
  k_ln<<<dim3(BS_), dim3(256), 0, stream>>>(ypre, ln_g, ln_b, ybf);
  k_out<<<dim3(BS_ / 128, D_ / 64), dim3(256), 0, stream>>>(ybf, wob, out);
}